// Round 15
// baseline (658.906 us; speedup 1.0000x reference)
//
#include <hip/hip_runtime.h>
#include <math.h>

#define T 512
#define B 128
#define KK 8
#define HH 32
#define PP 32

// ws layout (floats)
#define WS_GX    0             /* gx [dir*B+b][t][96] = 12582912 floats */
#define WS_GS    6291456       /* alias gx dir=1 half: gumbel noise [t][b][8], written after GRU */
#define WS_HSEQ  12582912
#define WS_LOGITS 0            /* alias gx dir=0 half: scaled logits [t][b][64], written after GRU */
#define WS_INIT  16777216
#define WS_YSEQ  16778240

// d_out layout (floats)
#define OUT_A    0
#define OUT_B    16777216
#define OUT_C    25165824
#define OUT_Q    58720256
#define OUT_LQ   75497472
#define OUT_LP   75563008

#define TINV 2.0f
#define PSTAY 0.9f
#define OFFV (0.1f / 7.0f)
#define DPS (PSTAY - OFFV)
#define LOG_INV_K (-2.0794415416798357f)

typedef float f4v __attribute__((ext_vector_type(4)));
typedef __attribute__((address_space(3))) float as3f;

// async DMA global->LDS, 16B/lane, opaque to compiler (no auto waitcnt insertion)
__device__ __forceinline__ void dma16(unsigned ldsbyte, int voffbyte, const void* sbase) {
    asm volatile("s_mov_b32 m0, %0\n\t"
                 "global_load_lds_dwordx4 %1, %2"
                 :: "s"(ldsbyte), "v"(voffbyte), "s"(sbase)
                 : "memory");
}
// stores kept in asm: compiler does not track them -> no per-iter vmcnt drains
__device__ __forceinline__ void st16(void* p, f4v v) {
    asm volatile("global_store_dwordx4 %0, %1, off" :: "v"(p), "v"(v) : "memory");
}
// pinned LDS read: output lives in registers, cannot be rematerialized at use
__device__ __forceinline__ f4v ldsr16(int addr) {
    f4v out;
    asm volatile("ds_read_b128 %0, %1" : "=v"(out) : "v"(addr));
    return out;
}
// pinned global loads: outputs live in registers; caller does counted vmcnt
__device__ __forceinline__ f4v ldg16(const void* p) {
    f4v out;
    asm volatile("global_load_dwordx4 %0, %1, off" : "=v"(out) : "v"(p) : "memory");
    return out;
}
__device__ __forceinline__ float ldg4(const void* p) {
    float out;
    asm volatile("global_load_dword %0, %1, off" : "=v"(out) : "v"(p) : "memory");
    return out;
}

// ---------------- Kernel A: gx tiled: W in regs, x tile in LDS --------------
__global__ __launch_bounds__(192) void gx_kernel(
    const float* __restrict__ a_seq,
    const float* __restrict__ wih_f, const float* __restrict__ bih_f,
    const float* __restrict__ wih_b, const float* __restrict__ bih_b,
    float* __restrict__ gx) {
    __shared__ float xt[64 * 32];
    int blk = blockIdx.x;
    int b = blk >> 3;
    int t0 = (blk & 7) << 6;
    int g = threadIdx.x;            // 0..191
    int dir = (g >= 96) ? 1 : 0;
    int gg = dir ? (g - 96) : g;
    const float* w = dir ? wih_b : wih_f;
    const float* bv = dir ? bih_b : bih_f;

    {
        const float4* src = (const float4*)(a_seq + ((size_t)b * T + t0) * PP);
        float4* dst = (float4*)xt;
        for (int idx = g; idx < 512; idx += 192) dst[idx] = src[idx];
    }
    float wreg[32];
#pragma unroll
    for (int q = 0; q < 8; ++q) {
        float4 wv = *(const float4*)(w + (size_t)gg * PP + q * 4);
        wreg[q * 4 + 0] = wv.x; wreg[q * 4 + 1] = wv.y;
        wreg[q * 4 + 2] = wv.z; wreg[q * 4 + 3] = wv.w;
    }
    float bias = bv[gg];
    __syncthreads();

    float* op = gx + ((size_t)(dir * B + b) * T + t0) * 96 + gg;
#pragma unroll 4
    for (int r = 0; r < 64; ++r) {
        const float4* xr = (const float4*)(xt + r * 32);
        float acc = bias;
#pragma unroll
        for (int q = 0; q < 8; ++q) {
            float4 xv = xr[q];
            acc = fmaf(xv.x, wreg[q * 4 + 0], acc);
            acc = fmaf(xv.y, wreg[q * 4 + 1], acc);
            acc = fmaf(xv.z, wreg[q * 4 + 2], acc);
            acc = fmaf(xv.w, wreg[q * 4 + 3], acc);
        }
        op[(size_t)r * 96] = acc;
    }
}

// ---------------- Kernel B: GRU scan (round-14 version, unchanged) ----------
__global__ __launch_bounds__(64, 1) void gru_kernel(
    const float* __restrict__ gx,
    const float* __restrict__ whh_f, const float* __restrict__ bhh_f,
    const float* __restrict__ whh_b, const float* __restrict__ bhh_b,
    float* __restrict__ hseq) {
    int cid = blockIdx.x;            // 0..255 = dir*128 + b
    int b = cid & 127;
    int dir = cid >> 7;
    int i = threadIdx.x & 31;
    const float* whh = dir ? whh_b : whh_f;
    const float* bhh = dir ? bhh_b : bhh_f;
    const float* gp0 = gx + (size_t)cid * (T * 96);

    f4v wr[8], wz[8], wn[8];
#pragma unroll
    for (int q = 0; q < 8; ++q) {
        wr[q] = ldg16(whh + (size_t)i * 32 + q * 4);
        wz[q] = ldg16(whh + (size_t)(32 + i) * 32 + q * 4);
        wn[q] = ldg16(whh + (size_t)(64 + i) * 32 + q * 4);
    }
    float bhr = ldg4(bhh + i);
    float bhz = ldg4(bhh + 32 + i);
    float bhn = ldg4(bhh + 64 + i);

    const float* p = gp0 + (dir ? (T - 1) * 96 : 0);
    int gstep = dir ? -96 : 96;
    int voff = (((dir ? (T - 1) : 0) * B + b) * 64 + dir * 32 + i) * 4;
    int vstep = dir ? -(B * 64 * 4) : (B * 64 * 4);

    float pxrA[8], pxzA[8], pxnA[8], pxrB[8], pxzB[8], pxnB[8];

#define LOADG(PR, PZ, PN, G0) do {                                             \
        _Pragma("unroll")                                                      \
        for (int u_ = 0; u_ < 8; ++u_) {                                       \
            int sc_ = (G0) * 8 + u_; if (sc_ > T - 1) sc_ = T - 1;             \
            const float* rp_ = p + sc_ * gstep;                                \
            PR[u_] = ldg4(rp_ + i);                                            \
            PZ[u_] = ldg4(rp_ + 32 + i);                                       \
            PN[u_] = ldg4(rp_ + 64 + i);                                       \
        }                                                                      \
    } while (0)

#define GWAIT(N) do {                                                          \
        asm volatile("s_waitcnt vmcnt(" #N ")" ::: "memory");                  \
        __builtin_amdgcn_sched_barrier(0);                                     \
    } while (0)

#define GSTEP(PR, PZ, PN, SLOT) do {                                           \
        float hj_[32];                                                         \
        _Pragma("unroll")                                                      \
        for (int jj = 0; jj < 32; ++jj)                                        \
            hj_[jj] = __uint_as_float(                                         \
                __builtin_amdgcn_readlane(__float_as_uint(h), jj));            \
        __builtin_amdgcn_sched_barrier(0);                                     \
        float hr_ = PR[SLOT] + bhr;                                            \
        float hz_ = PZ[SLOT] + bhz;                                            \
        float hn_ = bhn;                                                       \
        _Pragma("unroll")                                                      \
        for (int q_ = 0; q_ < 8; ++q_) {                                       \
            _Pragma("unroll")                                                  \
            for (int c_ = 0; c_ < 4; ++c_) {                                   \
                float hjv_ = hj_[q_ * 4 + c_];                                 \
                hr_ = fmaf(wr[q_][c_], hjv_, hr_);                             \
                hz_ = fmaf(wz[q_][c_], hjv_, hz_);                             \
                hn_ = fmaf(wn[q_][c_], hjv_, hn_);                             \
            }                                                                  \
        }                                                                      \
        float r_ = __builtin_amdgcn_rcpf(1.f + __expf(-hr_));                  \
        float z_ = __builtin_amdgcn_rcpf(1.f + __expf(-hz_));                  \
        float na_ = fmaf(r_, hn_, PN[SLOT]);                                   \
        float e2_ = __expf(-2.f * fabsf(na_));                                 \
        float n_ = copysignf((1.f - e2_) * __builtin_amdgcn_rcpf(1.f + e2_), na_); \
        h = fmaf(z_, h - n_, n_);                                              \
        asm volatile("global_store_dword %0, %1, %2"                           \
                     :: "v"(voff), "v"(h), "s"(hseq) : "memory");              \
        voff += vstep;                                                         \
    } while (0)

    LOADG(pxrA, pxzA, pxnA, 0);
    GWAIT(0);
    float h = 0.f;

    for (int gq = 0; gq < 32; ++gq) {
        LOADG(pxrB, pxzB, pxnB, 2 * gq + 1);
        GWAIT(32);
        GSTEP(pxrA, pxzA, pxnA, 0); GSTEP(pxrA, pxzA, pxnA, 1);
        GSTEP(pxrA, pxzA, pxnA, 2); GSTEP(pxrA, pxzA, pxnA, 3);
        GSTEP(pxrA, pxzA, pxnA, 4); GSTEP(pxrA, pxzA, pxnA, 5);
        GSTEP(pxrA, pxzA, pxnA, 6); GSTEP(pxrA, pxzA, pxnA, 7);
        LOADG(pxrA, pxzA, pxnA, 2 * gq + 2);
        GWAIT(32);
        GSTEP(pxrB, pxzB, pxnB, 0); GSTEP(pxrB, pxzB, pxnB, 1);
        GSTEP(pxrB, pxzB, pxnB, 2); GSTEP(pxrB, pxzB, pxnB, 3);
        GSTEP(pxrB, pxzB, pxnB, 4); GSTEP(pxrB, pxzB, pxnB, 5);
        GSTEP(pxrB, pxzB, pxnB, 6); GSTEP(pxrB, pxzB, pxnB, 7);
    }
#undef LOADG
#undef GWAIT
#undef GSTEP
}

// ---------------- Kernel C: logits (round-13 LDS-staged, unchanged) ---------
__global__ __launch_bounds__(256) void logits_kernel(
    const float* __restrict__ hseq,
    const float* __restrict__ wl, const float* __restrict__ bl,
    const float* __restrict__ wi, const float* __restrict__ bi,
    float* __restrict__ logits, float* __restrict__ initl) {
    __shared__ float wls[64 * 65];
    __shared__ float hrow[4][64];
    int tid = threadIdx.x;
    for (int i2 = tid; i2 < 1024; i2 += 256) {
        float4 v = ((const float4*)wl)[i2];
        int gr = i2 >> 4;
        int cc = (i2 & 15) * 4;
        float* d = &wls[gr * 65 + cc];
        d[0] = v.x; d[1] = v.y; d[2] = v.z; d[3] = v.w;
    }
    int q = tid >> 6;
    int tb = blockIdx.x * 4 + q;   // t*B + b
    int g = tid & 63;
    hrow[q][g] = hseq[(size_t)tb * 64 + g];
    __syncthreads();
    float acc = bl[g];
    const float* wrow = &wls[g * 65];
#pragma unroll
    for (int c = 0; c < 64; ++c) acc = fmaf(wrow[c], hrow[q][c], acc);
    logits[(size_t)tb * 64 + g] = acc * TINV;
    if (tb < B && g < 8) {
        float a2 = bi[g];
        const float* w2 = wi + (size_t)g * 64;
#pragma unroll
        for (int c = 0; c < 64; ++c) a2 = fmaf(w2[c], hrow[q][c], a2);
        initl[tb * 8 + g] = a2;
    }
}

// ---------------- Kernel G: gumbel noise [t][b][8], pre-scaled by 1/tau -----
__global__ __launch_bounds__(256) void gsc_kernel(
    const float* __restrict__ u0, const float* __restrict__ useq,
    float* __restrict__ gs) {
    int id = blockIdx.x * 256 + threadIdx.x;
    if (id >= T * B * KK) return;
    int j = id & 7;
    int b = (id >> 3) & 127;
    int t = id >> 10;
    float u = (t == 0) ? u0[b * 8 + j]
                       : useq[((size_t)b * (T - 1) + (t - 1)) * 8 + j];
    gs[id] = -logf(-logf(u)) * TINV;   // precise logf: u near 1 is ill-conditioned
}

// ---------------- Kernel D: scan, 2 interleaved batch chains per lane -------
// 2 blocks x 128 thr. Block owns 64 batches. Consumer lane r (r<32 stores;
// upper half duplicates) owns local batches r and r+32 — two independent
// recurrence chains interleaved per phase so dep chains overlap.
// Producer (wave 1): 18 DMA/phase (16 logits + 2 gs), loads-only FIFO,
// vmcnt(18) proves slot t landed; ring 3 x 18432 B. 511 barriers each side.
// Overwrite safety: slot (t-1)%3's reads retire at phase t-1's lgkmcnt(0),
// before barrier #t, before producer's ISSUE after barrier #t.
__global__ __launch_bounds__(128, 1) void scan_kernel(
    const float* __restrict__ logits, const float* __restrict__ initl,
    const float* __restrict__ gs, float* __restrict__ yseq) {
    __shared__ float lds[3][4608];   // 3 slots x (64*64 logits + 64*8 gs)
    int tid = threadIdx.x;
    int wave = tid >> 6;
    int r = tid & 63;
    int b0 = blockIdx.x * 64;        // 2 blocks x 64 batches

    unsigned ldsU = (unsigned)(unsigned long long)(as3f*)(&lds[0][0]);

#define ISSUE(tt, sl) do {                                                   \
        unsigned lb_ = ldsU + (unsigned)((sl) * 18432);                      \
        const char* bt_ = (const char*)logits + (size_t)(tt) * 32768;        \
        const char* gt_ = (const char*)gs + (size_t)(tt) * 4096;             \
        dma16(lb_ + 0 * 1024u, lof[0], bt_);                                 \
        dma16(lb_ + 1 * 1024u, lof[1], bt_);                                 \
        dma16(lb_ + 2 * 1024u, lof[2], bt_);                                 \
        dma16(lb_ + 3 * 1024u, lof[3], bt_);                                 \
        dma16(lb_ + 4 * 1024u, lof[4], bt_);                                 \
        dma16(lb_ + 5 * 1024u, lof[5], bt_);                                 \
        dma16(lb_ + 6 * 1024u, lof[6], bt_);                                 \
        dma16(lb_ + 7 * 1024u, lof[7], bt_);                                 \
        dma16(lb_ + 8 * 1024u, lof[8], bt_);                                 \
        dma16(lb_ + 9 * 1024u, lof[9], bt_);                                 \
        dma16(lb_ + 10 * 1024u, lof[10], bt_);                               \
        dma16(lb_ + 11 * 1024u, lof[11], bt_);                               \
        dma16(lb_ + 12 * 1024u, lof[12], bt_);                               \
        dma16(lb_ + 13 * 1024u, lof[13], bt_);                               \
        dma16(lb_ + 14 * 1024u, lof[14], bt_);                               \
        dma16(lb_ + 15 * 1024u, lof[15], bt_);                               \
        dma16(lb_ + 16384u, gof[0], gt_);                                    \
        dma16(lb_ + 17408u, gof[1], gt_);                                    \
    } while (0)

    if (wave == 1) {
        // ---------------- DMA producer wave ----------------
        int lof[16];
#pragma unroll
        for (int q = 0; q < 16; ++q) {
            int rr = q * 4 + (r >> 4);         // local tile row 0..63
            int cc = r & 15;                   // linear f4v col in LDS
            lof[q] = (((b0 + rr) * 64) + ((cc ^ (rr & 15)) << 2)) << 2;
        }
        int gof[2];
#pragma unroll
        for (int d = 0; d < 2; ++d) {
            int rg = d * 32 + (r >> 1);        // local row 0..63
            int cc = r & 1;
            gof[d] = (((b0 + rg) * 8) + ((cc ^ (rg & 1)) << 2)) << 2;
        }
        ISSUE(1, 1);
        ISSUE(2, 2);
        for (int t = 1; t < T; ++t) {
            asm volatile("s_waitcnt vmcnt(18)" ::: "memory");  // slot t landed
            __builtin_amdgcn_s_barrier();                      // #t
            if (t <= T - 2) {
                int tp = t + 2; if (tp > T - 1) tp = T - 1;
                ISSUE(tp, (t + 2) % 3);
            }
        }
        return;
    }

    // ---------------- compute consumer wave ----------------
    int rr31 = r & 31;
    int bA = b0 + rr31;              // global batch A
    int bB = b0 + 32 + rr31;         // global batch B
    int xk = rr31 & 15;              // same for both ( (r+32)&15 == r&15 )
    int gxk = rr31 & 1;
    unsigned baseA = ldsU + (unsigned)(rr31 * 256);
    unsigned baseB = ldsU + (unsigned)((rr31 + 32) * 256);
    unsigned gbA = ldsU + 16384u + (unsigned)(rr31 * 32);
    unsigned gbB = ldsU + 16384u + (unsigned)((rr31 + 32) * 32);

#define SREAD(LL, G0, G1, BASE, GB) do {                                     \
        _Pragma("unroll")                                                    \
        for (int m_ = 0; m_ < 16; ++m_)                                      \
            LL[m_] = ldsr16((int)(BASE + so_ + ((m_ ^ xk) << 4)));           \
        G0 = ldsr16((int)(GB + so_ + (gxk << 4)));                           \
        G1 = ldsr16((int)(GB + so_ + ((gxk ^ 1) << 4)));                     \
    } while (0)

#define SCOMP(LL, G0, G1, E, SINV, YP, tt) do {                              \
        float pl_[8];                                                        \
        _Pragma("unroll")                                                    \
        for (int j_ = 0; j_ < 8; ++j_) pl_[j_] = 0.f;                        \
        _Pragma("unroll")                                                    \
        for (int k_ = 0; k_ < 8; ++k_) {                                     \
            f4v w0_ = LL[2 * k_], w1_ = LL[2 * k_ + 1];                      \
            float ek_ = E[k_];                                               \
            pl_[0] = fmaf(ek_, w0_.x, pl_[0]); pl_[1] = fmaf(ek_, w0_.y, pl_[1]); \
            pl_[2] = fmaf(ek_, w0_.z, pl_[2]); pl_[3] = fmaf(ek_, w0_.w, pl_[3]); \
            pl_[4] = fmaf(ek_, w1_.x, pl_[4]); pl_[5] = fmaf(ek_, w1_.y, pl_[5]); \
            pl_[6] = fmaf(ek_, w1_.z, pl_[6]); pl_[7] = fmaf(ek_, w1_.w, pl_[7]); \
        }                                                                    \
        float gg_[8] = {G0.x, G0.y, G0.z, G0.w, G1.x, G1.y, G1.z, G1.w};     \
        float ss_ = 0.f;                                                     \
        _Pragma("unroll")                                                    \
        for (int j_ = 0; j_ < 8; ++j_) {                                     \
            float a_ = fmaf(pl_[j_], SINV, gg_[j_]);                         \
            E[j_] = __expf(a_);                                              \
            ss_ += E[j_];                                                    \
        }                                                                    \
        SINV = __builtin_amdgcn_rcpf(ss_);                                   \
        if (r < 32) {                                                        \
            f4v v0_ = (f4v){E[0] * SINV, E[1] * SINV, E[2] * SINV, E[3] * SINV}; \
            f4v v1_ = (f4v){E[4] * SINV, E[5] * SINV, E[6] * SINV, E[7] * SINV}; \
            st16(&YP[2 * (tt)], v0_);                                        \
            st16(&YP[2 * (tt) + 1], v1_);                                    \
        }                                                                    \
    } while (0)

#define T0INIT(BG, E, SINV, YP) do {                                         \
        const f4v* il4_ = (const f4v*)(initl + (BG) * 8);                    \
        f4v i0_ = il4_[0], i1_ = il4_[1];                                    \
        const f4v* g4_ = (const f4v*)(gs + (BG) * 8);                        \
        f4v G0_ = g4_[0], G1_ = g4_[1];                                      \
        float a_[8];                                                         \
        a_[0] = fmaf(i0_.x, TINV, G0_.x); a_[1] = fmaf(i0_.y, TINV, G0_.y);  \
        a_[2] = fmaf(i0_.z, TINV, G0_.z); a_[3] = fmaf(i0_.w, TINV, G0_.w);  \
        a_[4] = fmaf(i1_.x, TINV, G1_.x); a_[5] = fmaf(i1_.y, TINV, G1_.y);  \
        a_[6] = fmaf(i1_.z, TINV, G1_.z); a_[7] = fmaf(i1_.w, TINV, G1_.w);  \
        float ss_ = 0.f;                                                     \
        _Pragma("unroll")                                                    \
        for (int j_ = 0; j_ < 8; ++j_) { E[j_] = __expf(a_[j_]); ss_ += E[j_]; } \
        SINV = __builtin_amdgcn_rcpf(ss_);                                   \
        if (r < 32) {                                                        \
            f4v y0_ = (f4v){E[0] * SINV, E[1] * SINV, E[2] * SINV, E[3] * SINV}; \
            f4v y1_ = (f4v){E[4] * SINV, E[5] * SINV, E[6] * SINV, E[7] * SINV}; \
            st16(&YP[0], y0_);                                               \
            st16(&YP[1], y1_);                                               \
        }                                                                    \
    } while (0)

    f4v* ypA = (f4v*)(yseq + (size_t)bA * T * 8);
    f4v* ypB = (f4v*)(yseq + (size_t)bB * T * 8);
    float eA[8], eB[8];
    float sinvA, sinvB;

    T0INIT(bA, eA, sinvA, ypA);
    T0INIT(bB, eB, sinvB, ypB);

    f4v LA[16], LB[16], gaA, gbAv, gaB, gbBv;

    for (int t = 1; t < T; ++t) {
        __builtin_amdgcn_s_barrier();          // #t: slot t landed
        int so_ = (t % 3) * 18432;
        SREAD(LA, gaA, gbAv, baseA, gbA);      // 18 ds_reads (A)
        SREAD(LB, gaB, gbBv, baseB, gbB);      // 18 ds_reads (B)
        asm volatile("s_waitcnt lgkmcnt(15)" ::: "memory");   // A's 18 retired
        __builtin_amdgcn_sched_barrier(0);
        SCOMP(LA, gaA, gbAv, eA, sinvA, ypA, t);              // covers B's reads
        asm volatile("s_waitcnt lgkmcnt(0)" ::: "memory");
        __builtin_amdgcn_sched_barrier(0);
        SCOMP(LB, gaB, gbBv, eB, sinvB, ypB, t);
    }
#undef ISSUE
#undef SREAD
#undef SCOMP
#undef T0INIT
}

// ---------------- Kernel E: log_q / log_p (round-14 version, unchanged) -----
__global__ __launch_bounds__(256) void lqlp_kernel(
    const float* __restrict__ logits, const float* __restrict__ initl,
    const float* __restrict__ yseq,
    float* __restrict__ logq, float* __restrict__ logp) {
    int tid = blockIdx.x * 256 + threadIdx.x;   // (b*T + t)*8 + j
    int j = tid & 7;
    int row = tid >> 3;                          // b*T + t
    int b = row >> 9;
    int t = row & (T - 1);

    const float4* yt4 = (const float4*)(yseq + (size_t)row * 8);
    float4 ya = yt4[0], yb = yt4[1];
    float yt[8] = {ya.x, ya.y, ya.z, ya.w, yb.x, yb.y, yb.z, yb.w};

    float l[8];
    float lp;
    if (t == 0) {
        const float4* il4 = (const float4*)(initl + b * 8);
        float4 i0 = il4[0], i1 = il4[1];
        l[0] = i0.x; l[1] = i0.y; l[2] = i0.z; l[3] = i0.w;
        l[4] = i1.x; l[5] = i1.y; l[6] = i1.z; l[7] = i1.w;
        float sy = ((yt[0] + yt[1]) + (yt[2] + yt[3])) + ((yt[4] + yt[5]) + (yt[6] + yt[7]));
        lp = LOG_INV_K * sy;
    } else {
        const float4* yp4 = (const float4*)(yseq + (size_t)row * 8 - 8);
        float4 p0 = yp4[0], p1 = yp4[1];
        float ypv[8] = {p0.x, p0.y, p0.z, p0.w, p1.x, p1.y, p1.z, p1.w};
        float ypj = yseq[(size_t)row * 8 - 8 + j];
        const float4* L4 = (const float4*)(logits + ((size_t)t * B + b) * 64 + j * 8);
        float4 r0 = L4[0], r1 = L4[1];
        float c[8] = {ypj * r0.x, ypj * r0.y, ypj * r0.z, ypj * r0.w,
                      ypj * r1.x, ypj * r1.y, ypj * r1.z, ypj * r1.w};
#pragma unroll
        for (int s = 1; s <= 4; s <<= 1) {
#pragma unroll
            for (int m = 0; m < 8; ++m) c[m] += __shfl_xor(c[m], s, 64);
        }
#pragma unroll
        for (int m = 0; m < 8; ++m) l[m] = c[m] * 0.5f;
        float sy = ((ypv[0] + ypv[1]) + (ypv[2] + ypv[3])) + ((ypv[4] + ypv[5]) + (ypv[6] + ypv[7]));
        float acc = 0.f;
#pragma unroll
        for (int m = 0; m < 8; ++m) {
            float tp = fmaf(DPS, ypv[m], OFFV * sy);
            acc = fmaf(yt[m], logf(fmaxf(tp, 1e-8f)), acc);
        }
        lp = acc;
    }
    float m = fmaxf(fmaxf(fmaxf(l[0], l[1]), fmaxf(l[2], l[3])),
                    fmaxf(fmaxf(l[4], l[5]), fmaxf(l[6], l[7])));
    float se = 0.f;
#pragma unroll
    for (int m2 = 0; m2 < 8; ++m2) se += __expf(l[m2] - m);
    float lse = m + logf(se);
    float lq = 0.f;
#pragma unroll
    for (int m2 = 0; m2 < 8; ++m2) lq = fmaf(yt[m2], l[m2] - lse, lq);
    if (j == 0) {
        logq[row] = lq;
        logp[row] = lp;
    }
}

// ---------------- Kernel F: output einsums (round-10 version, unchanged) ----
__global__ __launch_bounds__(256) void out_kernel(
    const float* __restrict__ yseq,
    const float* __restrict__ A, const float* __restrict__ Bm,
    const float* __restrict__ C, const float* __restrict__ Q,
    float4* __restrict__ out4) {
    __shared__ float tab[6144];
    int tid = threadIdx.x;
    int bt0 = blockIdx.x * 64;
    {
        float4* t4 = (float4*)tab;
        const float4* A4 = (const float4*)A;
        const float4* B4 = (const float4*)Bm;
        const float4* Q4 = (const float4*)Q;
        const float4* C4 = (const float4*)C;
        for (int i2 = tid; i2 < 512; i2 += 256) t4[i2] = A4[i2];
        if (tid < 256) t4[512 + tid] = B4[tid];
        for (int i2 = tid; i2 < 512; i2 += 256) t4[768 + i2] = Q4[i2];
        if (tid < 128) t4[1280 + tid] = C4[tid];
        const float4* Y4 = (const float4*)(yseq + (size_t)bt0 * 8);
        if (tid < 128) t4[1408 + tid] = Y4[tid];
    }
    __syncthreads();

    int wave = tid >> 6;
    int lane = tid & 63;
    const float4* t4 = (const float4*)tab;

    if (wave == 0 || wave == 1) {
        int tbase = (wave == 0) ? 0 : 768;
        size_t obase = (wave == 0) ? (size_t)(OUT_A / 4) : (size_t)(OUT_Q / 4);
        float4 wreg[8];
#pragma unroll
        for (int k = 0; k < 8; ++k) wreg[k] = t4[tbase + k * 64 + lane];
        for (int bt = 0; bt < 64; ++bt) {
            float4 ya = t4[1408 + bt * 2];
            float4 yb = t4[1408 + bt * 2 + 1];
            float yk[8] = {ya.x, ya.y, ya.z, ya.w, yb.x, yb.y, yb.z, yb.w};
            float4 v = make_float4(0.f, 0.f, 0.f, 0.f);
#pragma unroll
            for (int k = 0; k < 8; ++k) {
                v.x = fmaf(yk[k], wreg[k].x, v.x);
                v.y = fmaf(yk[k], wreg[k].y, v.y);
                v.z = fmaf(yk[k], wreg[k].z, v.z);
                v.w = fmaf(yk[k], wreg[k].w, v.w);
            }
            out4[obase + (size_t)(bt0 + bt) * 64 + lane] = v;
        }
    } else if (wave == 2) {
        if (lane < 32) {
            float4 wreg[8];
#pragma unroll
            for (int k = 0; k < 8; ++k) wreg[k] = t4[512 + k * 32 + lane];
            for (int bt = 0; bt < 64; ++bt) {
                float4 ya = t4[1408 + bt * 2];
                float4 yb = t4[1408 + bt * 2 + 1];
                float yk[8] = {ya.x, ya.y, ya.z, ya.w, yb.x, yb.y, yb.z, yb.w};
                float4 v = make_float4(0.f, 0.f, 0.f, 0.f);
#pragma unroll
                for (int k = 0; k < 8; ++k) {
                    v.x = fmaf(yk[k], wreg[k].x, v.x);
                    v.y = fmaf(yk[k], wreg[k].y, v.y);
                    v.z = fmaf(yk[k], wreg[k].z, v.z);
                    v.w = fmaf(yk[k], wreg[k].w, v.w);
                }
                out4[(size_t)(OUT_B / 4) + (size_t)(bt0 + bt) * 32 + lane] = v;
            }
        } else {
            float4 c0 = t4[1280 + (lane - 32)];
            for (int bt = 0; bt < 64; ++bt)
                out4[(size_t)(OUT_C / 4) + (size_t)(bt0 + bt) * 128 + (lane - 32)] = c0;
        }
    } else {
        float4 c1 = t4[1280 + 32 + lane];
        float4 c2 = (lane < 32) ? t4[1280 + 96 + lane] : make_float4(0.f, 0.f, 0.f, 0.f);
        for (int bt = 0; bt < 64; ++bt) {
            out4[(size_t)(OUT_C / 4) + (size_t)(bt0 + bt) * 128 + 32 + lane] = c1;
            if (lane < 32)
                out4[(size_t)(OUT_C / 4) + (size_t)(bt0 + bt) * 128 + 96 + lane] = c2;
        }
    }
}

extern "C" void kernel_launch(void* const* d_in, const int* in_sizes, int n_in,
                              void* d_out, int out_size, void* d_ws, size_t ws_size,
                              hipStream_t stream) {
    const float* a_seq = (const float*)d_in[0];
    const float* A     = (const float*)d_in[1];
    const float* Bmat  = (const float*)d_in[2];
    const float* C     = (const float*)d_in[3];
    const float* Q     = (const float*)d_in[4];
    const float* wih_f = (const float*)d_in[5];
    const float* whh_f = (const float*)d_in[6];
    const float* bih_f = (const float*)d_in[7];
    const float* bhh_f = (const float*)d_in[8];
    const float* wih_b = (const float*)d_in[9];
    const float* whh_b = (const float*)d_in[10];
    const float* bih_b = (const float*)d_in[11];
    const float* bhh_b = (const float*)d_in[12];
    const float* wl    = (const float*)d_in[13];
    const float* bl    = (const float*)d_in[14];
    const float* wi    = (const float*)d_in[15];
    const float* bi    = (const float*)d_in[16];
    const float* u0    = (const float*)d_in[17];
    const float* useq  = (const float*)d_in[18];

    float* ws = (float*)d_ws;
    float* gx     = ws + WS_GX;
    float* gsb    = ws + WS_GS;       // aliases gx dir=1 half (written after GRU)
    float* hseq   = ws + WS_HSEQ;
    float* logits = ws + WS_LOGITS;   // aliases gx dir=0 half (written after GRU)
    float* initl  = ws + WS_INIT;
    float* yseq   = ws + WS_YSEQ;

    float* outf = (float*)d_out;
    float* logq = outf + OUT_LQ;
    float* logp = outf + OUT_LP;

    gx_kernel<<<B * (T / 64), 192, 0, stream>>>(a_seq, wih_f, bih_f, wih_b, bih_b, gx);
    gru_kernel<<<256, 64, 0, stream>>>(gx, whh_f, bhh_f, whh_b, bhh_b, hseq);
    {
        int total = B * T * KK;
        gsc_kernel<<<(total + 255) / 256, 256, 0, stream>>>(u0, useq, gsb);
    }
    logits_kernel<<<T * B / 4, 256, 0, stream>>>(hseq, wl, bl, wi, bi, logits, initl);
    scan_kernel<<<2, 128, 0, stream>>>(logits, initl, gsb, yseq);
    lqlp_kernel<<<B * T * KK / 256, 256, 0, stream>>>(logits, initl, yseq, logq, logp);
    out_kernel<<<B * T / 64, 256, 0, stream>>>(yseq, A, Bmat, C, Q, (float4*)d_out);
}

// Round 16
// 483.523 us; speedup vs baseline: 1.3627x; 1.3627x over previous
//
#include <hip/hip_runtime.h>
#include <math.h>

#define T 512
#define B 128
#define KK 8
#define HH 32
#define PP 32

// ws layout (floats)
#define WS_GX    0             /* gx [dir*B+b][t][96] = 12582912 floats */
#define WS_GS    6291456       /* alias gx dir=1 half: gumbel noise [t][b][8], written after GRU */
#define WS_HSEQ  12582912
#define WS_LOGITS 0            /* alias gx dir=0 half: scaled logits [t][b][64], written after GRU */
#define WS_INIT  16777216
#define WS_YSEQ  16778240

// d_out layout (floats)
#define OUT_A    0
#define OUT_B    16777216
#define OUT_C    25165824
#define OUT_Q    58720256
#define OUT_LQ   75497472
#define OUT_LP   75563008

#define TINV 2.0f
#define PSTAY 0.9f
#define OFFV (0.1f / 7.0f)
#define DPS (PSTAY - OFFV)
#define LOG_INV_K (-2.0794415416798357f)

typedef float f4v __attribute__((ext_vector_type(4)));
typedef __attribute__((address_space(3))) float as3f;

// async DMA global->LDS, 16B/lane, opaque to compiler (no auto waitcnt insertion)
__device__ __forceinline__ void dma16(unsigned ldsbyte, int voffbyte, const void* sbase) {
    asm volatile("s_mov_b32 m0, %0\n\t"
                 "global_load_lds_dwordx4 %1, %2"
                 :: "s"(ldsbyte), "v"(voffbyte), "s"(sbase)
                 : "memory");
}
// stores kept in asm: compiler does not track them -> no per-iter vmcnt drains
__device__ __forceinline__ void st16(void* p, f4v v) {
    asm volatile("global_store_dwordx4 %0, %1, off" :: "v"(p), "v"(v) : "memory");
}
// pinned LDS read: output lives in registers, cannot be rematerialized at use
__device__ __forceinline__ f4v ldsr16(int addr) {
    f4v out;
    asm volatile("ds_read_b128 %0, %1" : "=v"(out) : "v"(addr));
    return out;
}
// pinned global loads: outputs live in registers; caller does counted vmcnt
__device__ __forceinline__ f4v ldg16(const void* p) {
    f4v out;
    asm volatile("global_load_dwordx4 %0, %1, off" : "=v"(out) : "v"(p) : "memory");
    return out;
}
__device__ __forceinline__ float ldg4(const void* p) {
    float out;
    asm volatile("global_load_dword %0, %1, off" : "=v"(out) : "v"(p) : "memory");
    return out;
}

// ---------------- Kernel A: gx tiled + gsc folded in as extra blocks --------
// blocks 0..1023: gx tile work. blocks 1024..3754: gumbel noise precompute.
__global__ __launch_bounds__(192) void gx_kernel(
    const float* __restrict__ a_seq,
    const float* __restrict__ wih_f, const float* __restrict__ bih_f,
    const float* __restrict__ wih_b, const float* __restrict__ bih_b,
    float* __restrict__ gx,
    const float* __restrict__ u0, const float* __restrict__ useq,
    float* __restrict__ gs) {
    __shared__ float xt[64 * 32];
    if (blockIdx.x >= 1024) {
        int id = (blockIdx.x - 1024) * 192 + threadIdx.x;
        if (id < T * B * KK) {
            int j = id & 7;
            int b = (id >> 3) & 127;
            int t = id >> 10;
            float u = (t == 0) ? u0[b * 8 + j]
                               : useq[((size_t)b * (T - 1) + (t - 1)) * 8 + j];
            gs[id] = -logf(-logf(u)) * TINV;   // precise logf (u near 1 ill-conditioned)
        }
        return;
    }
    int blk = blockIdx.x;
    int b = blk >> 3;
    int t0 = (blk & 7) << 6;
    int g = threadIdx.x;            // 0..191
    int dir = (g >= 96) ? 1 : 0;
    int gg = dir ? (g - 96) : g;
    const float* w = dir ? wih_b : wih_f;
    const float* bv = dir ? bih_b : bih_f;

    {
        const float4* src = (const float4*)(a_seq + ((size_t)b * T + t0) * PP);
        float4* dst = (float4*)xt;
        for (int idx = g; idx < 512; idx += 192) dst[idx] = src[idx];
    }
    float wreg[32];
#pragma unroll
    for (int q = 0; q < 8; ++q) {
        float4 wv = *(const float4*)(w + (size_t)gg * PP + q * 4);
        wreg[q * 4 + 0] = wv.x; wreg[q * 4 + 1] = wv.y;
        wreg[q * 4 + 2] = wv.z; wreg[q * 4 + 3] = wv.w;
    }
    float bias = bv[gg];
    __syncthreads();

    float* op = gx + ((size_t)(dir * B + b) * T + t0) * 96 + gg;
#pragma unroll 4
    for (int r = 0; r < 64; ++r) {
        const float4* xr = (const float4*)(xt + r * 32);
        float acc = bias;
#pragma unroll
        for (int q = 0; q < 8; ++q) {
            float4 xv = xr[q];
            acc = fmaf(xv.x, wreg[q * 4 + 0], acc);
            acc = fmaf(xv.y, wreg[q * 4 + 1], acc);
            acc = fmaf(xv.z, wreg[q * 4 + 2], acc);
            acc = fmaf(xv.w, wreg[q * 4 + 3], acc);
        }
        op[(size_t)r * 96] = acc;
    }
}

// ---------------- Kernel B: GRU scan (round-14 version, unchanged) ----------
__global__ __launch_bounds__(64, 1) void gru_kernel(
    const float* __restrict__ gx,
    const float* __restrict__ whh_f, const float* __restrict__ bhh_f,
    const float* __restrict__ whh_b, const float* __restrict__ bhh_b,
    float* __restrict__ hseq) {
    int cid = blockIdx.x;            // 0..255 = dir*128 + b
    int b = cid & 127;
    int dir = cid >> 7;
    int i = threadIdx.x & 31;
    const float* whh = dir ? whh_b : whh_f;
    const float* bhh = dir ? bhh_b : bhh_f;
    const float* gp0 = gx + (size_t)cid * (T * 96);

    f4v wr[8], wz[8], wn[8];
#pragma unroll
    for (int q = 0; q < 8; ++q) {
        wr[q] = ldg16(whh + (size_t)i * 32 + q * 4);
        wz[q] = ldg16(whh + (size_t)(32 + i) * 32 + q * 4);
        wn[q] = ldg16(whh + (size_t)(64 + i) * 32 + q * 4);
    }
    float bhr = ldg4(bhh + i);
    float bhz = ldg4(bhh + 32 + i);
    float bhn = ldg4(bhh + 64 + i);

    const float* p = gp0 + (dir ? (T - 1) * 96 : 0);
    int gstep = dir ? -96 : 96;
    int voff = (((dir ? (T - 1) : 0) * B + b) * 64 + dir * 32 + i) * 4;
    int vstep = dir ? -(B * 64 * 4) : (B * 64 * 4);

    float pxrA[8], pxzA[8], pxnA[8], pxrB[8], pxzB[8], pxnB[8];

#define LOADG(PR, PZ, PN, G0) do {                                             \
        _Pragma("unroll")                                                      \
        for (int u_ = 0; u_ < 8; ++u_) {                                       \
            int sc_ = (G0) * 8 + u_; if (sc_ > T - 1) sc_ = T - 1;             \
            const float* rp_ = p + sc_ * gstep;                                \
            PR[u_] = ldg4(rp_ + i);                                            \
            PZ[u_] = ldg4(rp_ + 32 + i);                                       \
            PN[u_] = ldg4(rp_ + 64 + i);                                       \
        }                                                                      \
    } while (0)

#define GWAIT(N) do {                                                          \
        asm volatile("s_waitcnt vmcnt(" #N ")" ::: "memory");                  \
        __builtin_amdgcn_sched_barrier(0);                                     \
    } while (0)

#define GSTEP(PR, PZ, PN, SLOT) do {                                           \
        float hj_[32];                                                         \
        _Pragma("unroll")                                                      \
        for (int jj = 0; jj < 32; ++jj)                                        \
            hj_[jj] = __uint_as_float(                                         \
                __builtin_amdgcn_readlane(__float_as_uint(h), jj));            \
        __builtin_amdgcn_sched_barrier(0);                                     \
        float hr_ = PR[SLOT] + bhr;                                            \
        float hz_ = PZ[SLOT] + bhz;                                            \
        float hn_ = bhn;                                                       \
        _Pragma("unroll")                                                      \
        for (int q_ = 0; q_ < 8; ++q_) {                                       \
            _Pragma("unroll")                                                  \
            for (int c_ = 0; c_ < 4; ++c_) {                                   \
                float hjv_ = hj_[q_ * 4 + c_];                                 \
                hr_ = fmaf(wr[q_][c_], hjv_, hr_);                             \
                hz_ = fmaf(wz[q_][c_], hjv_, hz_);                             \
                hn_ = fmaf(wn[q_][c_], hjv_, hn_);                             \
            }                                                                  \
        }                                                                      \
        float r_ = __builtin_amdgcn_rcpf(1.f + __expf(-hr_));                  \
        float z_ = __builtin_amdgcn_rcpf(1.f + __expf(-hz_));                  \
        float na_ = fmaf(r_, hn_, PN[SLOT]);                                   \
        float e2_ = __expf(-2.f * fabsf(na_));                                 \
        float n_ = copysignf((1.f - e2_) * __builtin_amdgcn_rcpf(1.f + e2_), na_); \
        h = fmaf(z_, h - n_, n_);                                              \
        asm volatile("global_store_dword %0, %1, %2"                           \
                     :: "v"(voff), "v"(h), "s"(hseq) : "memory");              \
        voff += vstep;                                                         \
    } while (0)

    LOADG(pxrA, pxzA, pxnA, 0);
    GWAIT(0);
    float h = 0.f;

    for (int gq = 0; gq < 32; ++gq) {
        LOADG(pxrB, pxzB, pxnB, 2 * gq + 1);
        GWAIT(32);
        GSTEP(pxrA, pxzA, pxnA, 0); GSTEP(pxrA, pxzA, pxnA, 1);
        GSTEP(pxrA, pxzA, pxnA, 2); GSTEP(pxrA, pxzA, pxnA, 3);
        GSTEP(pxrA, pxzA, pxnA, 4); GSTEP(pxrA, pxzA, pxnA, 5);
        GSTEP(pxrA, pxzA, pxnA, 6); GSTEP(pxrA, pxzA, pxnA, 7);
        LOADG(pxrA, pxzA, pxnA, 2 * gq + 2);
        GWAIT(32);
        GSTEP(pxrB, pxzB, pxnB, 0); GSTEP(pxrB, pxzB, pxnB, 1);
        GSTEP(pxrB, pxzB, pxnB, 2); GSTEP(pxrB, pxzB, pxnB, 3);
        GSTEP(pxrB, pxzB, pxnB, 4); GSTEP(pxrB, pxzB, pxnB, 5);
        GSTEP(pxrB, pxzB, pxnB, 6); GSTEP(pxrB, pxzB, pxnB, 7);
    }
#undef LOADG
#undef GWAIT
#undef GSTEP
}

// ---------------- Kernel C: logits (round-13 LDS-staged, unchanged) ---------
__global__ __launch_bounds__(256) void logits_kernel(
    const float* __restrict__ hseq,
    const float* __restrict__ wl, const float* __restrict__ bl,
    const float* __restrict__ wi, const float* __restrict__ bi,
    float* __restrict__ logits, float* __restrict__ initl) {
    __shared__ float wls[64 * 65];
    __shared__ float hrow[4][64];
    int tid = threadIdx.x;
    for (int i2 = tid; i2 < 1024; i2 += 256) {
        float4 v = ((const float4*)wl)[i2];
        int gr = i2 >> 4;
        int cc = (i2 & 15) * 4;
        float* d = &wls[gr * 65 + cc];
        d[0] = v.x; d[1] = v.y; d[2] = v.z; d[3] = v.w;
    }
    int q = tid >> 6;
    int tb = blockIdx.x * 4 + q;   // t*B + b
    int g = tid & 63;
    hrow[q][g] = hseq[(size_t)tb * 64 + g];
    __syncthreads();
    float acc = bl[g];
    const float* wrow = &wls[g * 65];
#pragma unroll
    for (int c = 0; c < 64; ++c) acc = fmaf(wrow[c], hrow[q][c], acc);
    logits[(size_t)tb * 64 + g] = acc * TINV;
    if (tb < B && g < 8) {
        float a2 = bi[g];
        const float* w2 = wi + (size_t)g * 64;
#pragma unroll
        for (int c = 0; c < 64; ++c) a2 = fmaf(w2[c], hrow[q][c], a2);
        initl[tb * 8 + g] = a2;
    }
}

// ---------------- Kernel D: y-only scan, producer/consumer wave split -------
// (byte-identical to round 13/14 — known-good at 183 us)
__global__ __launch_bounds__(128, 1) void scan_kernel(
    const float* __restrict__ logits, const float* __restrict__ initl,
    const float* __restrict__ gs, float* __restrict__ yseq) {
    __shared__ float lds[6][2304];   // 6 slots x (32*64 logits + 32*8 gs)
    int tid = threadIdx.x;
    int wave = tid >> 6;
    int r = tid & 63;
    int b0 = blockIdx.x * 32;
    int b = b0 + (r & 31);
    int k15 = r & 15;

    unsigned ldsU = (unsigned)(unsigned long long)(as3f*)(&lds[0][0]);

#define ISSUE(tt, sl) do {                                                   \
        unsigned lb_ = ldsU + (unsigned)((sl) * 9216);                       \
        const char* bt_ = (const char*)logits + (size_t)(tt) * 32768;        \
        const char* gt_ = (const char*)gs + (size_t)(tt) * 4096;             \
        dma16(lb_ + 0 * 1024u, lof[0], bt_);                                 \
        dma16(lb_ + 1 * 1024u, lof[1], bt_);                                 \
        dma16(lb_ + 2 * 1024u, lof[2], bt_);                                 \
        dma16(lb_ + 3 * 1024u, lof[3], bt_);                                 \
        dma16(lb_ + 4 * 1024u, lof[4], bt_);                                 \
        dma16(lb_ + 5 * 1024u, lof[5], bt_);                                 \
        dma16(lb_ + 6 * 1024u, lof[6], bt_);                                 \
        dma16(lb_ + 7 * 1024u, lof[7], bt_);                                 \
        dma16(lb_ + 8192u, gof, gt_);                                        \
    } while (0)

    if (wave == 1) {
        // ---------------- DMA producer wave ----------------
        int lof[8];
#pragma unroll
        for (int q = 0; q < 8; ++q) {
            int rr = q * 4 + (r >> 4);         // tile row 0..31
            int cc = r & 15;                   // linear f4v col in LDS
            lof[q] = (((b0 + rr) * 64) + ((cc ^ (rr & 15)) << 2)) << 2;
        }
        int gof;
        {
            int rg = r >> 1;
            int cc = r & 1;
            gof = (((b0 + rg) * 8) + ((cc ^ (rg & 1)) << 2)) << 2;
        }
#pragma unroll
        for (int p = 1; p <= 5; ++p) ISSUE(p, p);
        asm volatile("s_waitcnt vmcnt(36)" ::: "memory");   // slot 1 landed
        __builtin_amdgcn_s_barrier();                        // #0
        for (int t = 1; t < T; ++t) {
            asm volatile("s_waitcnt vmcnt(27)" ::: "memory"); // slot t+1 landed
            __builtin_amdgcn_s_barrier();                     // #t
            int tp = t + 5; if (tp > T - 1) tp = T - 1;
            ISSUE(tp, (t + 5) % 6);
        }
        return;
    }

    // ---------------- compute consumer wave ----------------
    unsigned rbase = ldsU + (unsigned)((r & 31) * 256);
    unsigned gbase = ldsU + 8192u + (unsigned)((r & 31) * 32);

#define SREAD(LL, GA, GB, tt) do {                                           \
        int so_ = ((tt) % 6) * 9216;                                         \
        _Pragma("unroll")                                                    \
        for (int m_ = 0; m_ < 16; ++m_)                                      \
            LL[m_] = ldsr16((int)(rbase + so_ + ((m_ ^ k15) << 4)));         \
        GA = ldsr16((int)(gbase + so_ + ((r & 1) << 4)));                    \
        GB = ldsr16((int)(gbase + so_ + (((r & 1) ^ 1) << 4)));              \
    } while (0)

#define LWAIT() do {                                                         \
        asm volatile("s_waitcnt lgkmcnt(0)" ::: "memory");                   \
        __builtin_amdgcn_sched_barrier(0);                                   \
    } while (0)

#define SCOMP(LL, GA, GB, tt) do {                                           \
        float pl_[8];                                                        \
        _Pragma("unroll")                                                    \
        for (int j_ = 0; j_ < 8; ++j_) pl_[j_] = 0.f;                        \
        _Pragma("unroll")                                                    \
        for (int k_ = 0; k_ < 8; ++k_) {                                     \
            f4v w0_ = LL[2 * k_], w1_ = LL[2 * k_ + 1];                      \
            float ek_ = e[k_];                                               \
            pl_[0] = fmaf(ek_, w0_.x, pl_[0]); pl_[1] = fmaf(ek_, w0_.y, pl_[1]); \
            pl_[2] = fmaf(ek_, w0_.z, pl_[2]); pl_[3] = fmaf(ek_, w0_.w, pl_[3]); \
            pl_[4] = fmaf(ek_, w1_.x, pl_[4]); pl_[5] = fmaf(ek_, w1_.y, pl_[5]); \
            pl_[6] = fmaf(ek_, w1_.z, pl_[6]); pl_[7] = fmaf(ek_, w1_.w, pl_[7]); \
        }                                                                    \
        float gg_[8] = {GA.x, GA.y, GA.z, GA.w, GB.x, GB.y, GB.z, GB.w};     \
        float ss_ = 0.f;                                                     \
        _Pragma("unroll")                                                    \
        for (int j_ = 0; j_ < 8; ++j_) {                                     \
            float a_ = fmaf(pl_[j_], sinv, gg_[j_]);                         \
            e[j_] = __expf(a_);                                              \
            ss_ += e[j_];                                                    \
        }                                                                    \
        sinv = __builtin_amdgcn_rcpf(ss_);                                   \
        if (r < 32) {                                                        \
            f4v v0_ = (f4v){e[0] * sinv, e[1] * sinv, e[2] * sinv, e[3] * sinv}; \
            f4v v1_ = (f4v){e[4] * sinv, e[5] * sinv, e[6] * sinv, e[7] * sinv}; \
            st16(&yp[2 * (tt)], v0_);                                        \
            st16(&yp[2 * (tt) + 1], v1_);                                    \
        }                                                                    \
    } while (0)

    f4v* yp = (f4v*)(yseq + (size_t)b * T * 8);
    float e[8];
    float sinv;

    // ---- t = 0 from initl + gs[0] (plain loads, compiler-tracked) ----
    {
        const f4v* il4 = (const f4v*)(initl + b * 8);
        f4v i0 = il4[0], i1 = il4[1];
        const f4v* g4 = (const f4v*)(gs + b * 8);
        f4v G0 = g4[0], G1 = g4[1];
        float a[8];
        a[0] = fmaf(i0.x, TINV, G0.x); a[1] = fmaf(i0.y, TINV, G0.y);
        a[2] = fmaf(i0.z, TINV, G0.z); a[3] = fmaf(i0.w, TINV, G0.w);
        a[4] = fmaf(i1.x, TINV, G1.x); a[5] = fmaf(i1.y, TINV, G1.y);
        a[6] = fmaf(i1.z, TINV, G1.z); a[7] = fmaf(i1.w, TINV, G1.w);
        float ssum = 0.f;
#pragma unroll
        for (int j = 0; j < 8; ++j) { e[j] = __expf(a[j]); ssum += e[j]; }
        sinv = __builtin_amdgcn_rcpf(ssum);
        if (r < 32) {
            f4v y0v = (f4v){e[0] * sinv, e[1] * sinv, e[2] * sinv, e[3] * sinv};
            f4v y1v = (f4v){e[4] * sinv, e[5] * sinv, e[6] * sinv, e[7] * sinv};
            st16(&yp[0], y0v);
            st16(&yp[1], y1v);
        }
    }

    f4v LA[16], LB[16], gaA, gbA, gaB, gbB;

    __builtin_amdgcn_s_barrier();      // #0: slot 1 landed (producer vmcnt(36))
    SREAD(LA, gaA, gbA, 1);

    for (int t = 1; t < T - 1; t += 2) {
        __builtin_amdgcn_s_barrier();  // #t: slot t+1 landed
        LWAIT();                       // prior phase's SREAD retired
        SREAD(LB, gaB, gbB, t + 1);
        SCOMP(LA, gaA, gbA, t);

        __builtin_amdgcn_s_barrier();  // #t+1: slot t+2 landed
        LWAIT();
        SREAD(LA, gaA, gbA, t + 2);
        SCOMP(LB, gaB, gbB, t + 1);
    }
    __builtin_amdgcn_s_barrier();      // #511
    LWAIT();
    SCOMP(LA, gaA, gbA, T - 1);
#undef ISSUE
#undef SREAD
#undef LWAIT
#undef SCOMP
}

// ---------------- Kernel E: log_q / log_p (round-14 version, unchanged) -----
__global__ __launch_bounds__(256) void lqlp_kernel(
    const float* __restrict__ logits, const float* __restrict__ initl,
    const float* __restrict__ yseq,
    float* __restrict__ logq, float* __restrict__ logp) {
    int tid = blockIdx.x * 256 + threadIdx.x;   // (b*T + t)*8 + j
    int j = tid & 7;
    int row = tid >> 3;                          // b*T + t
    int b = row >> 9;
    int t = row & (T - 1);

    const float4* yt4 = (const float4*)(yseq + (size_t)row * 8);
    float4 ya = yt4[0], yb = yt4[1];
    float yt[8] = {ya.x, ya.y, ya.z, ya.w, yb.x, yb.y, yb.z, yb.w};

    float l[8];
    float lp;
    if (t == 0) {
        const float4* il4 = (const float4*)(initl + b * 8);
        float4 i0 = il4[0], i1 = il4[1];
        l[0] = i0.x; l[1] = i0.y; l[2] = i0.z; l[3] = i0.w;
        l[4] = i1.x; l[5] = i1.y; l[6] = i1.z; l[7] = i1.w;
        float sy = ((yt[0] + yt[1]) + (yt[2] + yt[3])) + ((yt[4] + yt[5]) + (yt[6] + yt[7]));
        lp = LOG_INV_K * sy;
    } else {
        const float4* yp4 = (const float4*)(yseq + (size_t)row * 8 - 8);
        float4 p0 = yp4[0], p1 = yp4[1];
        float ypv[8] = {p0.x, p0.y, p0.z, p0.w, p1.x, p1.y, p1.z, p1.w};
        float ypj = yseq[(size_t)row * 8 - 8 + j];
        const float4* L4 = (const float4*)(logits + ((size_t)t * B + b) * 64 + j * 8);
        float4 r0 = L4[0], r1 = L4[1];
        float c[8] = {ypj * r0.x, ypj * r0.y, ypj * r0.z, ypj * r0.w,
                      ypj * r1.x, ypj * r1.y, ypj * r1.z, ypj * r1.w};
#pragma unroll
        for (int s = 1; s <= 4; s <<= 1) {
#pragma unroll
            for (int m = 0; m < 8; ++m) c[m] += __shfl_xor(c[m], s, 64);
        }
#pragma unroll
        for (int m = 0; m < 8; ++m) l[m] = c[m] * 0.5f;
        float sy = ((ypv[0] + ypv[1]) + (ypv[2] + ypv[3])) + ((ypv[4] + ypv[5]) + (ypv[6] + ypv[7]));
        float acc = 0.f;
#pragma unroll
        for (int m = 0; m < 8; ++m) {
            float tp = fmaf(DPS, ypv[m], OFFV * sy);
            acc = fmaf(yt[m], logf(fmaxf(tp, 1e-8f)), acc);
        }
        lp = acc;
    }
    float m = fmaxf(fmaxf(fmaxf(l[0], l[1]), fmaxf(l[2], l[3])),
                    fmaxf(fmaxf(l[4], l[5]), fmaxf(l[6], l[7])));
    float se = 0.f;
#pragma unroll
    for (int m2 = 0; m2 < 8; ++m2) se += __expf(l[m2] - m);
    float lse = m + logf(se);
    float lq = 0.f;
#pragma unroll
    for (int m2 = 0; m2 < 8; ++m2) lq = fmaf(yt[m2], l[m2] - lse, lq);
    if (j == 0) {
        logq[row] = lq;
        logp[row] = lp;
    }
}

// ---------------- Kernel F: output einsums (round-10 version, unchanged) ----
__global__ __launch_bounds__(256) void out_kernel(
    const float* __restrict__ yseq,
    const float* __restrict__ A, const float* __restrict__ Bm,
    const float* __restrict__ C, const float* __restrict__ Q,
    float4* __restrict__ out4) {
    __shared__ float tab[6144];
    int tid = threadIdx.x;
    int bt0 = blockIdx.x * 64;
    {
        float4* t4 = (float4*)tab;
        const float4* A4 = (const float4*)A;
        const float4* B4 = (const float4*)Bm;
        const float4* Q4 = (const float4*)Q;
        const float4* C4 = (const float4*)C;
        for (int i2 = tid; i2 < 512; i2 += 256) t4[i2] = A4[i2];
        if (tid < 256) t4[512 + tid] = B4[tid];
        for (int i2 = tid; i2 < 512; i2 += 256) t4[768 + i2] = Q4[i2];
        if (tid < 128) t4[1280 + tid] = C4[tid];
        const float4* Y4 = (const float4*)(yseq + (size_t)bt0 * 8);
        if (tid < 128) t4[1408 + tid] = Y4[tid];
    }
    __syncthreads();

    int wave = tid >> 6;
    int lane = tid & 63;
    const float4* t4 = (const float4*)tab;

    if (wave == 0 || wave == 1) {
        int tbase = (wave == 0) ? 0 : 768;
        size_t obase = (wave == 0) ? (size_t)(OUT_A / 4) : (size_t)(OUT_Q / 4);
        float4 wreg[8];
#pragma unroll
        for (int k = 0; k < 8; ++k) wreg[k] = t4[tbase + k * 64 + lane];
        for (int bt = 0; bt < 64; ++bt) {
            float4 ya = t4[1408 + bt * 2];
            float4 yb = t4[1408 + bt * 2 + 1];
            float yk[8] = {ya.x, ya.y, ya.z, ya.w, yb.x, yb.y, yb.z, yb.w};
            float4 v = make_float4(0.f, 0.f, 0.f, 0.f);
#pragma unroll
            for (int k = 0; k < 8; ++k) {
                v.x = fmaf(yk[k], wreg[k].x, v.x);
                v.y = fmaf(yk[k], wreg[k].y, v.y);
                v.z = fmaf(yk[k], wreg[k].z, v.z);
                v.w = fmaf(yk[k], wreg[k].w, v.w);
            }
            out4[obase + (size_t)(bt0 + bt) * 64 + lane] = v;
        }
    } else if (wave == 2) {
        if (lane < 32) {
            float4 wreg[8];
#pragma unroll
            for (int k = 0; k < 8; ++k) wreg[k] = t4[512 + k * 32 + lane];
            for (int bt = 0; bt < 64; ++bt) {
                float4 ya = t4[1408 + bt * 2];
                float4 yb = t4[1408 + bt * 2 + 1];
                float yk[8] = {ya.x, ya.y, ya.z, ya.w, yb.x, yb.y, yb.z, yb.w};
                float4 v = make_float4(0.f, 0.f, 0.f, 0.f);
#pragma unroll
                for (int k = 0; k < 8; ++k) {
                    v.x = fmaf(yk[k], wreg[k].x, v.x);
                    v.y = fmaf(yk[k], wreg[k].y, v.y);
                    v.z = fmaf(yk[k], wreg[k].z, v.z);
                    v.w = fmaf(yk[k], wreg[k].w, v.w);
                }
                out4[(size_t)(OUT_B / 4) + (size_t)(bt0 + bt) * 32 + lane] = v;
            }
        } else {
            float4 c0 = t4[1280 + (lane - 32)];
            for (int bt = 0; bt < 64; ++bt)
                out4[(size_t)(OUT_C / 4) + (size_t)(bt0 + bt) * 128 + (lane - 32)] = c0;
        }
    } else {
        float4 c1 = t4[1280 + 32 + lane];
        float4 c2 = (lane < 32) ? t4[1280 + 96 + lane] : make_float4(0.f, 0.f, 0.f, 0.f);
        for (int bt = 0; bt < 64; ++bt) {
            out4[(size_t)(OUT_C / 4) + (size_t)(bt0 + bt) * 128 + 32 + lane] = c1;
            if (lane < 32)
                out4[(size_t)(OUT_C / 4) + (size_t)(bt0 + bt) * 128 + 96 + lane] = c2;
        }
    }
}

extern "C" void kernel_launch(void* const* d_in, const int* in_sizes, int n_in,
                              void* d_out, int out_size, void* d_ws, size_t ws_size,
                              hipStream_t stream) {
    const float* a_seq = (const float*)d_in[0];
    const float* A     = (const float*)d_in[1];
    const float* Bmat  = (const float*)d_in[2];
    const float* C     = (const float*)d_in[3];
    const float* Q     = (const float*)d_in[4];
    const float* wih_f = (const float*)d_in[5];
    const float* whh_f = (const float*)d_in[6];
    const float* bih_f = (const float*)d_in[7];
    const float* bhh_f = (const float*)d_in[8];
    const float* wih_b = (const float*)d_in[9];
    const float* whh_b = (const float*)d_in[10];
    const float* bih_b = (const float*)d_in[11];
    const float* bhh_b = (const float*)d_in[12];
    const float* wl    = (const float*)d_in[13];
    const float* bl    = (const float*)d_in[14];
    const float* wi    = (const float*)d_in[15];
    const float* bi    = (const float*)d_in[16];
    const float* u0    = (const float*)d_in[17];
    const float* useq  = (const float*)d_in[18];

    float* ws = (float*)d_ws;
    float* gx     = ws + WS_GX;
    float* gsb    = ws + WS_GS;       // aliases gx dir=1 half? NO - separate region below
    float* hseq   = ws + WS_HSEQ;
    float* logits = ws + WS_LOGITS;   // aliases gx dir=0 half (written after GRU)
    float* initl  = ws + WS_INIT;
    float* yseq   = ws + WS_YSEQ;

    // NOTE: gs is now written by gx_kernel (merged gsc), i.e. BEFORE the GRU
    // consumes gx — so it must NOT alias gx. Place it after yseq instead.
    float* gs2 = ws + WS_YSEQ + (size_t)B * T * KK;   // 524288 floats, fits ws

    float* outf = (float*)d_out;
    float* logq = outf + OUT_LQ;
    float* logp = outf + OUT_LP;

    (void)gsb;
    gx_kernel<<<1024 + (T * B * KK + 191) / 192, 192, 0, stream>>>(
        a_seq, wih_f, bih_f, wih_b, bih_b, gx, u0, useq, gs2);
    gru_kernel<<<256, 64, 0, stream>>>(gx, whh_f, bhh_f, whh_b, bhh_b, hseq);
    logits_kernel<<<T * B / 4, 256, 0, stream>>>(hseq, wl, bl, wi, bi, logits, initl);
    scan_kernel<<<4, 128, 0, stream>>>(logits, initl, gs2, yseq);
    lqlp_kernel<<<B * T * KK / 256, 256, 0, stream>>>(logits, initl, yseq, logq, logp);
    out_kernel<<<B * T / 64, 256, 0, stream>>>(yseq, A, Bmat, C, Q, (float4*)d_out);
}

// Round 17
// 454.475 us; speedup vs baseline: 1.4498x; 1.0639x over previous
//
#include <hip/hip_runtime.h>
#include <math.h>

#define T 512
#define B 128
#define KK 8
#define HH 32
#define PP 32

// ws layout (floats)
#define WS_GX    0             /* gx [dir*B+b][t][96] = 12582912 floats */
#define WS_HSEQ  12582912
#define WS_LOGITS 0            /* alias gx dir=0 half: scaled logits [t][b][64], written after GRU */
#define WS_INIT  16777216
#define WS_YSEQ  16778240

// d_out layout (floats)
#define OUT_A    0
#define OUT_B    16777216
#define OUT_C    25165824
#define OUT_Q    58720256
#define OUT_LQ   75497472
#define OUT_LP   75563008

#define TINV 2.0f
#define PSTAY 0.9f
#define OFFV (0.1f / 7.0f)
#define DPS (PSTAY - OFFV)
#define LOG_INV_K (-2.0794415416798357f)

typedef float f4v __attribute__((ext_vector_type(4)));
typedef __attribute__((address_space(3))) float as3f;

// async DMA global->LDS, 16B/lane, opaque to compiler (no auto waitcnt insertion)
__device__ __forceinline__ void dma16(unsigned ldsbyte, int voffbyte, const void* sbase) {
    asm volatile("s_mov_b32 m0, %0\n\t"
                 "global_load_lds_dwordx4 %1, %2"
                 :: "s"(ldsbyte), "v"(voffbyte), "s"(sbase)
                 : "memory");
}
// stores kept in asm: compiler does not track them -> no per-iter vmcnt drains
__device__ __forceinline__ void st16(void* p, f4v v) {
    asm volatile("global_store_dwordx4 %0, %1, off" :: "v"(p), "v"(v) : "memory");
}
// pinned LDS read: output lives in registers, cannot be rematerialized at use
__device__ __forceinline__ f4v ldsr16(int addr) {
    f4v out;
    asm volatile("ds_read_b128 %0, %1" : "=v"(out) : "v"(addr));
    return out;
}
// pinned global loads: outputs live in registers; caller does counted vmcnt
__device__ __forceinline__ f4v ldg16(const void* p) {
    f4v out;
    asm volatile("global_load_dwordx4 %0, %1, off" : "=v"(out) : "v"(p) : "memory");
    return out;
}
__device__ __forceinline__ float ldg4(const void* p) {
    float out;
    asm volatile("global_load_dword %0, %1, off" : "=v"(out) : "v"(p) : "memory");
    return out;
}

// ---------------- Kernel A: gx tiled + gsc folded in as extra blocks --------
__global__ __launch_bounds__(192) void gx_kernel(
    const float* __restrict__ a_seq,
    const float* __restrict__ wih_f, const float* __restrict__ bih_f,
    const float* __restrict__ wih_b, const float* __restrict__ bih_b,
    float* __restrict__ gx,
    const float* __restrict__ u0, const float* __restrict__ useq,
    float* __restrict__ gs) {
    __shared__ float xt[64 * 32];
    if (blockIdx.x >= 1024) {
        int id = (blockIdx.x - 1024) * 192 + threadIdx.x;
        if (id < T * B * KK) {
            int j = id & 7;
            int b = (id >> 3) & 127;
            int t = id >> 10;
            float u = (t == 0) ? u0[b * 8 + j]
                               : useq[((size_t)b * (T - 1) + (t - 1)) * 8 + j];
            gs[id] = -logf(-logf(u)) * TINV;   // precise logf (u near 1 ill-conditioned)
        }
        return;
    }
    int blk = blockIdx.x;
    int b = blk >> 3;
    int t0 = (blk & 7) << 6;
    int g = threadIdx.x;            // 0..191
    int dir = (g >= 96) ? 1 : 0;
    int gg = dir ? (g - 96) : g;
    const float* w = dir ? wih_b : wih_f;
    const float* bv = dir ? bih_b : bih_f;

    {
        const float4* src = (const float4*)(a_seq + ((size_t)b * T + t0) * PP);
        float4* dst = (float4*)xt;
        for (int idx = g; idx < 512; idx += 192) dst[idx] = src[idx];
    }
    float wreg[32];
#pragma unroll
    for (int q = 0; q < 8; ++q) {
        float4 wv = *(const float4*)(w + (size_t)gg * PP + q * 4);
        wreg[q * 4 + 0] = wv.x; wreg[q * 4 + 1] = wv.y;
        wreg[q * 4 + 2] = wv.z; wreg[q * 4 + 3] = wv.w;
    }
    float bias = bv[gg];
    __syncthreads();

    float* op = gx + ((size_t)(dir * B + b) * T + t0) * 96 + gg;
#pragma unroll 4
    for (int r = 0; r < 64; ++r) {
        const float4* xr = (const float4*)(xt + r * 32);
        float acc = bias;
#pragma unroll
        for (int q = 0; q < 8; ++q) {
            float4 xv = xr[q];
            acc = fmaf(xv.x, wreg[q * 4 + 0], acc);
            acc = fmaf(xv.y, wreg[q * 4 + 1], acc);
            acc = fmaf(xv.z, wreg[q * 4 + 2], acc);
            acc = fmaf(xv.w, wreg[q * 4 + 3], acc);
        }
        op[(size_t)r * 96] = acc;
    }
}

// ---------------- Kernel B: GRU scan, split accumulator chains --------------
// ONLY change vs round 16: per-gate accumulation uses 4 independent chains
// (8 fma each) + pairwise combine — dependency chain per step drops from
// ~32 fma deep (~192 cyc) to ~8 fma + 2 add (~60 cyc). Issue count unchanged.
__global__ __launch_bounds__(64, 1) void gru_kernel(
    const float* __restrict__ gx,
    const float* __restrict__ whh_f, const float* __restrict__ bhh_f,
    const float* __restrict__ whh_b, const float* __restrict__ bhh_b,
    float* __restrict__ hseq) {
    int cid = blockIdx.x;            // 0..255 = dir*128 + b
    int b = cid & 127;
    int dir = cid >> 7;
    int i = threadIdx.x & 31;
    const float* whh = dir ? whh_b : whh_f;
    const float* bhh = dir ? bhh_b : bhh_f;
    const float* gp0 = gx + (size_t)cid * (T * 96);

    f4v wr[8], wz[8], wn[8];
#pragma unroll
    for (int q = 0; q < 8; ++q) {
        wr[q] = ldg16(whh + (size_t)i * 32 + q * 4);
        wz[q] = ldg16(whh + (size_t)(32 + i) * 32 + q * 4);
        wn[q] = ldg16(whh + (size_t)(64 + i) * 32 + q * 4);
    }
    float bhr = ldg4(bhh + i);
    float bhz = ldg4(bhh + 32 + i);
    float bhn = ldg4(bhh + 64 + i);

    const float* p = gp0 + (dir ? (T - 1) * 96 : 0);
    int gstep = dir ? -96 : 96;
    int voff = (((dir ? (T - 1) : 0) * B + b) * 64 + dir * 32 + i) * 4;
    int vstep = dir ? -(B * 64 * 4) : (B * 64 * 4);

    float pxrA[8], pxzA[8], pxnA[8], pxrB[8], pxzB[8], pxnB[8];

#define LOADG(PR, PZ, PN, G0) do {                                             \
        _Pragma("unroll")                                                      \
        for (int u_ = 0; u_ < 8; ++u_) {                                       \
            int sc_ = (G0) * 8 + u_; if (sc_ > T - 1) sc_ = T - 1;             \
            const float* rp_ = p + sc_ * gstep;                                \
            PR[u_] = ldg4(rp_ + i);                                            \
            PZ[u_] = ldg4(rp_ + 32 + i);                                       \
            PN[u_] = ldg4(rp_ + 64 + i);                                       \
        }                                                                      \
    } while (0)

#define GWAIT(N) do {                                                          \
        asm volatile("s_waitcnt vmcnt(" #N ")" ::: "memory");                  \
        __builtin_amdgcn_sched_barrier(0);                                     \
    } while (0)

#define GSTEP(PR, PZ, PN, SLOT) do {                                           \
        float hj_[32];                                                         \
        _Pragma("unroll")                                                      \
        for (int jj = 0; jj < 32; ++jj)                                        \
            hj_[jj] = __uint_as_float(                                         \
                __builtin_amdgcn_readlane(__float_as_uint(h), jj));            \
        __builtin_amdgcn_sched_barrier(0);                                     \
        float r0_ = PR[SLOT] + bhr, r1_ = 0.f, r2_ = 0.f, r3_ = 0.f;           \
        float z0_ = PZ[SLOT] + bhz, z1_ = 0.f, z2_ = 0.f, z3_ = 0.f;           \
        float n0_ = bhn, n1_ = 0.f, n2_ = 0.f, n3_ = 0.f;                      \
        _Pragma("unroll")                                                      \
        for (int q_ = 0; q_ < 2; ++q_) {                                       \
            _Pragma("unroll")                                                  \
            for (int c_ = 0; c_ < 4; ++c_) {                                   \
                float hv_ = hj_[q_ * 4 + c_];                                  \
                r0_ = fmaf(wr[q_][c_], hv_, r0_);                              \
                z0_ = fmaf(wz[q_][c_], hv_, z0_);                              \
                n0_ = fmaf(wn[q_][c_], hv_, n0_);                              \
            }                                                                  \
        }                                                                      \
        _Pragma("unroll")                                                      \
        for (int q_ = 2; q_ < 4; ++q_) {                                       \
            _Pragma("unroll")                                                  \
            for (int c_ = 0; c_ < 4; ++c_) {                                   \
                float hv_ = hj_[q_ * 4 + c_];                                  \
                r1_ = fmaf(wr[q_][c_], hv_, r1_);                              \
                z1_ = fmaf(wz[q_][c_], hv_, z1_);                              \
                n1_ = fmaf(wn[q_][c_], hv_, n1_);                              \
            }                                                                  \
        }                                                                      \
        _Pragma("unroll")                                                      \
        for (int q_ = 4; q_ < 6; ++q_) {                                       \
            _Pragma("unroll")                                                  \
            for (int c_ = 0; c_ < 4; ++c_) {                                   \
                float hv_ = hj_[q_ * 4 + c_];                                  \
                r2_ = fmaf(wr[q_][c_], hv_, r2_);                              \
                z2_ = fmaf(wz[q_][c_], hv_, z2_);                              \
                n2_ = fmaf(wn[q_][c_], hv_, n2_);                              \
            }                                                                  \
        }                                                                      \
        _Pragma("unroll")                                                      \
        for (int q_ = 6; q_ < 8; ++q_) {                                       \
            _Pragma("unroll")                                                  \
            for (int c_ = 0; c_ < 4; ++c_) {                                   \
                float hv_ = hj_[q_ * 4 + c_];                                  \
                r3_ = fmaf(wr[q_][c_], hv_, r3_);                              \
                z3_ = fmaf(wz[q_][c_], hv_, z3_);                              \
                n3_ = fmaf(wn[q_][c_], hv_, n3_);                              \
            }                                                                  \
        }                                                                      \
        float hr_ = (r0_ + r1_) + (r2_ + r3_);                                 \
        float hz_ = (z0_ + z1_) + (z2_ + z3_);                                 \
        float hn_ = (n0_ + n1_) + (n2_ + n3_);                                 \
        float r_ = __builtin_amdgcn_rcpf(1.f + __expf(-hr_));                  \
        float z_ = __builtin_amdgcn_rcpf(1.f + __expf(-hz_));                  \
        float na_ = fmaf(r_, hn_, PN[SLOT]);                                   \
        float e2_ = __expf(-2.f * fabsf(na_));                                 \
        float n_ = copysignf((1.f - e2_) * __builtin_amdgcn_rcpf(1.f + e2_), na_); \
        h = fmaf(z_, h - n_, n_);                                              \
        asm volatile("global_store_dword %0, %1, %2"                           \
                     :: "v"(voff), "v"(h), "s"(hseq) : "memory");              \
        voff += vstep;                                                         \
    } while (0)

    LOADG(pxrA, pxzA, pxnA, 0);
    GWAIT(0);
    float h = 0.f;

    for (int gq = 0; gq < 32; ++gq) {
        LOADG(pxrB, pxzB, pxnB, 2 * gq + 1);
        GWAIT(32);
        GSTEP(pxrA, pxzA, pxnA, 0); GSTEP(pxrA, pxzA, pxnA, 1);
        GSTEP(pxrA, pxzA, pxnA, 2); GSTEP(pxrA, pxzA, pxnA, 3);
        GSTEP(pxrA, pxzA, pxnA, 4); GSTEP(pxrA, pxzA, pxnA, 5);
        GSTEP(pxrA, pxzA, pxnA, 6); GSTEP(pxrA, pxzA, pxnA, 7);
        LOADG(pxrA, pxzA, pxnA, 2 * gq + 2);
        GWAIT(32);
        GSTEP(pxrB, pxzB, pxnB, 0); GSTEP(pxrB, pxzB, pxnB, 1);
        GSTEP(pxrB, pxzB, pxnB, 2); GSTEP(pxrB, pxzB, pxnB, 3);
        GSTEP(pxrB, pxzB, pxnB, 4); GSTEP(pxrB, pxzB, pxnB, 5);
        GSTEP(pxrB, pxzB, pxnB, 6); GSTEP(pxrB, pxzB, pxnB, 7);
    }
#undef LOADG
#undef GWAIT
#undef GSTEP
}

// ---------------- Kernel C: logits (round-13 LDS-staged, unchanged) ---------
__global__ __launch_bounds__(256) void logits_kernel(
    const float* __restrict__ hseq,
    const float* __restrict__ wl, const float* __restrict__ bl,
    const float* __restrict__ wi, const float* __restrict__ bi,
    float* __restrict__ logits, float* __restrict__ initl) {
    __shared__ float wls[64 * 65];
    __shared__ float hrow[4][64];
    int tid = threadIdx.x;
    for (int i2 = tid; i2 < 1024; i2 += 256) {
        float4 v = ((const float4*)wl)[i2];
        int gr = i2 >> 4;
        int cc = (i2 & 15) * 4;
        float* d = &wls[gr * 65 + cc];
        d[0] = v.x; d[1] = v.y; d[2] = v.z; d[3] = v.w;
    }
    int q = tid >> 6;
    int tb = blockIdx.x * 4 + q;   // t*B + b
    int g = tid & 63;
    hrow[q][g] = hseq[(size_t)tb * 64 + g];
    __syncthreads();
    float acc = bl[g];
    const float* wrow = &wls[g * 65];
#pragma unroll
    for (int c = 0; c < 64; ++c) acc = fmaf(wrow[c], hrow[q][c], acc);
    logits[(size_t)tb * 64 + g] = acc * TINV;
    if (tb < B && g < 8) {
        float a2 = bi[g];
        const float* w2 = wi + (size_t)g * 64;
#pragma unroll
        for (int c = 0; c < 64; ++c) a2 = fmaf(w2[c], hrow[q][c], a2);
        initl[tb * 8 + g] = a2;
    }
}

// ---------------- Kernel D: y-only scan, producer/consumer wave split -------
// (byte-identical to round 13/14/16 — known-good at 183 us)
__global__ __launch_bounds__(128, 1) void scan_kernel(
    const float* __restrict__ logits, const float* __restrict__ initl,
    const float* __restrict__ gs, float* __restrict__ yseq) {
    __shared__ float lds[6][2304];   // 6 slots x (32*64 logits + 32*8 gs)
    int tid = threadIdx.x;
    int wave = tid >> 6;
    int r = tid & 63;
    int b0 = blockIdx.x * 32;
    int b = b0 + (r & 31);
    int k15 = r & 15;

    unsigned ldsU = (unsigned)(unsigned long long)(as3f*)(&lds[0][0]);

#define ISSUE(tt, sl) do {                                                   \
        unsigned lb_ = ldsU + (unsigned)((sl) * 9216);                       \
        const char* bt_ = (const char*)logits + (size_t)(tt) * 32768;        \
        const char* gt_ = (const char*)gs + (size_t)(tt) * 4096;             \
        dma16(lb_ + 0 * 1024u, lof[0], bt_);                                 \
        dma16(lb_ + 1 * 1024u, lof[1], bt_);                                 \
        dma16(lb_ + 2 * 1024u, lof[2], bt_);                                 \
        dma16(lb_ + 3 * 1024u, lof[3], bt_);                                 \
        dma16(lb_ + 4 * 1024u, lof[4], bt_);                                 \
        dma16(lb_ + 5 * 1024u, lof[5], bt_);                                 \
        dma16(lb_ + 6 * 1024u, lof[6], bt_);                                 \
        dma16(lb_ + 7 * 1024u, lof[7], bt_);                                 \
        dma16(lb_ + 8192u, gof, gt_);                                        \
    } while (0)

    if (wave == 1) {
        // ---------------- DMA producer wave ----------------
        int lof[8];
#pragma unroll
        for (int q = 0; q < 8; ++q) {
            int rr = q * 4 + (r >> 4);         // tile row 0..31
            int cc = r & 15;                   // linear f4v col in LDS
            lof[q] = (((b0 + rr) * 64) + ((cc ^ (rr & 15)) << 2)) << 2;
        }
        int gof;
        {
            int rg = r >> 1;
            int cc = r & 1;
            gof = (((b0 + rg) * 8) + ((cc ^ (rg & 1)) << 2)) << 2;
        }
#pragma unroll
        for (int p = 1; p <= 5; ++p) ISSUE(p, p);
        asm volatile("s_waitcnt vmcnt(36)" ::: "memory");   // slot 1 landed
        __builtin_amdgcn_s_barrier();                        // #0
        for (int t = 1; t < T; ++t) {
            asm volatile("s_waitcnt vmcnt(27)" ::: "memory"); // slot t+1 landed
            __builtin_amdgcn_s_barrier();                     // #t
            int tp = t + 5; if (tp > T - 1) tp = T - 1;
            ISSUE(tp, (t + 5) % 6);
        }
        return;
    }

    // ---------------- compute consumer wave ----------------
    unsigned rbase = ldsU + (unsigned)((r & 31) * 256);
    unsigned gbase = ldsU + 8192u + (unsigned)((r & 31) * 32);

#define SREAD(LL, GA, GB, tt) do {                                           \
        int so_ = ((tt) % 6) * 9216;                                         \
        _Pragma("unroll")                                                    \
        for (int m_ = 0; m_ < 16; ++m_)                                      \
            LL[m_] = ldsr16((int)(rbase + so_ + ((m_ ^ k15) << 4)));         \
        GA = ldsr16((int)(gbase + so_ + ((r & 1) << 4)));                    \
        GB = ldsr16((int)(gbase + so_ + (((r & 1) ^ 1) << 4)));              \
    } while (0)

#define LWAIT() do {                                                         \
        asm volatile("s_waitcnt lgkmcnt(0)" ::: "memory");                   \
        __builtin_amdgcn_sched_barrier(0);                                   \
    } while (0)

#define SCOMP(LL, GA, GB, tt) do {                                           \
        float pl_[8];                                                        \
        _Pragma("unroll")                                                    \
        for (int j_ = 0; j_ < 8; ++j_) pl_[j_] = 0.f;                        \
        _Pragma("unroll")                                                    \
        for (int k_ = 0; k_ < 8; ++k_) {                                     \
            f4v w0_ = LL[2 * k_], w1_ = LL[2 * k_ + 1];                      \
            float ek_ = e[k_];                                               \
            pl_[0] = fmaf(ek_, w0_.x, pl_[0]); pl_[1] = fmaf(ek_, w0_.y, pl_[1]); \
            pl_[2] = fmaf(ek_, w0_.z, pl_[2]); pl_[3] = fmaf(ek_, w0_.w, pl_[3]); \
            pl_[4] = fmaf(ek_, w1_.x, pl_[4]); pl_[5] = fmaf(ek_, w1_.y, pl_[5]); \
            pl_[6] = fmaf(ek_, w1_.z, pl_[6]); pl_[7] = fmaf(ek_, w1_.w, pl_[7]); \
        }                                                                    \
        float gg_[8] = {GA.x, GA.y, GA.z, GA.w, GB.x, GB.y, GB.z, GB.w};     \
        float ss_ = 0.f;                                                     \
        _Pragma("unroll")                                                    \
        for (int j_ = 0; j_ < 8; ++j_) {                                     \
            float a_ = fmaf(pl_[j_], sinv, gg_[j_]);                         \
            e[j_] = __expf(a_);                                              \
            ss_ += e[j_];                                                    \
        }                                                                    \
        sinv = __builtin_amdgcn_rcpf(ss_);                                   \
        if (r < 32) {                                                        \
            f4v v0_ = (f4v){e[0] * sinv, e[1] * sinv, e[2] * sinv, e[3] * sinv}; \
            f4v v1_ = (f4v){e[4] * sinv, e[5] * sinv, e[6] * sinv, e[7] * sinv}; \
            st16(&yp[2 * (tt)], v0_);                                        \
            st16(&yp[2 * (tt) + 1], v1_);                                    \
        }                                                                    \
    } while (0)

    f4v* yp = (f4v*)(yseq + (size_t)b * T * 8);
    float e[8];
    float sinv;

    // ---- t = 0 from initl + gs[0] (plain loads, compiler-tracked) ----
    {
        const f4v* il4 = (const f4v*)(initl + b * 8);
        f4v i0 = il4[0], i1 = il4[1];
        const f4v* g4 = (const f4v*)(gs + b * 8);
        f4v G0 = g4[0], G1 = g4[1];
        float a[8];
        a[0] = fmaf(i0.x, TINV, G0.x); a[1] = fmaf(i0.y, TINV, G0.y);
        a[2] = fmaf(i0.z, TINV, G0.z); a[3] = fmaf(i0.w, TINV, G0.w);
        a[4] = fmaf(i1.x, TINV, G1.x); a[5] = fmaf(i1.y, TINV, G1.y);
        a[6] = fmaf(i1.z, TINV, G1.z); a[7] = fmaf(i1.w, TINV, G1.w);
        float ssum = 0.f;
#pragma unroll
        for (int j = 0; j < 8; ++j) { e[j] = __expf(a[j]); ssum += e[j]; }
        sinv = __builtin_amdgcn_rcpf(ssum);
        if (r < 32) {
            f4v y0v = (f4v){e[0] * sinv, e[1] * sinv, e[2] * sinv, e[3] * sinv};
            f4v y1v = (f4v){e[4] * sinv, e[5] * sinv, e[6] * sinv, e[7] * sinv};
            st16(&yp[0], y0v);
            st16(&yp[1], y1v);
        }
    }

    f4v LA[16], LB[16], gaA, gbA, gaB, gbB;

    __builtin_amdgcn_s_barrier();      // #0: slot 1 landed (producer vmcnt(36))
    SREAD(LA, gaA, gbA, 1);

    for (int t = 1; t < T - 1; t += 2) {
        __builtin_amdgcn_s_barrier();  // #t: slot t+1 landed
        LWAIT();                       // prior phase's SREAD retired
        SREAD(LB, gaB, gbB, t + 1);
        SCOMP(LA, gaA, gbA, t);

        __builtin_amdgcn_s_barrier();  // #t+1: slot t+2 landed
        LWAIT();
        SREAD(LA, gaA, gbA, t + 2);
        SCOMP(LB, gaB, gbB, t + 1);
    }
    __builtin_amdgcn_s_barrier();      // #511
    LWAIT();
    SCOMP(LA, gaA, gbA, T - 1);
#undef ISSUE
#undef SREAD
#undef LWAIT
#undef SCOMP
}

// ---------------- Kernel E: log_q / log_p (round-14 version, unchanged) -----
__global__ __launch_bounds__(256) void lqlp_kernel(
    const float* __restrict__ logits, const float* __restrict__ initl,
    const float* __restrict__ yseq,
    float* __restrict__ logq, float* __restrict__ logp) {
    int tid = blockIdx.x * 256 + threadIdx.x;   // (b*T + t)*8 + j
    int j = tid & 7;
    int row = tid >> 3;                          // b*T + t
    int b = row >> 9;
    int t = row & (T - 1);

    const float4* yt4 = (const float4*)(yseq + (size_t)row * 8);
    float4 ya = yt4[0], yb = yt4[1];
    float yt[8] = {ya.x, ya.y, ya.z, ya.w, yb.x, yb.y, yb.z, yb.w};

    float l[8];
    float lp;
    if (t == 0) {
        const float4* il4 = (const float4*)(initl + b * 8);
        float4 i0 = il4[0], i1 = il4[1];
        l[0] = i0.x; l[1] = i0.y; l[2] = i0.z; l[3] = i0.w;
        l[4] = i1.x; l[5] = i1.y; l[6] = i1.z; l[7] = i1.w;
        float sy = ((yt[0] + yt[1]) + (yt[2] + yt[3])) + ((yt[4] + yt[5]) + (yt[6] + yt[7]));
        lp = LOG_INV_K * sy;
    } else {
        const float4* yp4 = (const float4*)(yseq + (size_t)row * 8 - 8);
        float4 p0 = yp4[0], p1 = yp4[1];
        float ypv[8] = {p0.x, p0.y, p0.z, p0.w, p1.x, p1.y, p1.z, p1.w};
        float ypj = yseq[(size_t)row * 8 - 8 + j];
        const float4* L4 = (const float4*)(logits + ((size_t)t * B + b) * 64 + j * 8);
        float4 r0 = L4[0], r1 = L4[1];
        float c[8] = {ypj * r0.x, ypj * r0.y, ypj * r0.z, ypj * r0.w,
                      ypj * r1.x, ypj * r1.y, ypj * r1.z, ypj * r1.w};
#pragma unroll
        for (int s = 1; s <= 4; s <<= 1) {
#pragma unroll
            for (int m = 0; m < 8; ++m) c[m] += __shfl_xor(c[m], s, 64);
        }
#pragma unroll
        for (int m = 0; m < 8; ++m) l[m] = c[m] * 0.5f;
        float sy = ((ypv[0] + ypv[1]) + (ypv[2] + ypv[3])) + ((ypv[4] + ypv[5]) + (ypv[6] + ypv[7]));
        float acc = 0.f;
#pragma unroll
        for (int m = 0; m < 8; ++m) {
            float tp = fmaf(DPS, ypv[m], OFFV * sy);
            acc = fmaf(yt[m], logf(fmaxf(tp, 1e-8f)), acc);
        }
        lp = acc;
    }
    float m = fmaxf(fmaxf(fmaxf(l[0], l[1]), fmaxf(l[2], l[3])),
                    fmaxf(fmaxf(l[4], l[5]), fmaxf(l[6], l[7])));
    float se = 0.f;
#pragma unroll
    for (int m2 = 0; m2 < 8; ++m2) se += __expf(l[m2] - m);
    float lse = m + logf(se);
    float lq = 0.f;
#pragma unroll
    for (int m2 = 0; m2 < 8; ++m2) lq = fmaf(yt[m2], l[m2] - lse, lq);
    if (j == 0) {
        logq[row] = lq;
        logp[row] = lp;
    }
}

// ---------------- Kernel F: output einsums (round-10 version, unchanged) ----
__global__ __launch_bounds__(256) void out_kernel(
    const float* __restrict__ yseq,
    const float* __restrict__ A, const float* __restrict__ Bm,
    const float* __restrict__ C, const float* __restrict__ Q,
    float4* __restrict__ out4) {
    __shared__ float tab[6144];
    int tid = threadIdx.x;
    int bt0 = blockIdx.x * 64;
    {
        float4* t4 = (float4*)tab;
        const float4* A4 = (const float4*)A;
        const float4* B4 = (const float4*)Bm;
        const float4* Q4 = (const float4*)Q;
        const float4* C4 = (const float4*)C;
        for (int i2 = tid; i2 < 512; i2 += 256) t4[i2] = A4[i2];
        if (tid < 256) t4[512 + tid] = B4[tid];
        for (int i2 = tid; i2 < 512; i2 += 256) t4[768 + i2] = Q4[i2];
        if (tid < 128) t4[1280 + tid] = C4[tid];
        const float4* Y4 = (const float4*)(yseq + (size_t)bt0 * 8);
        if (tid < 128) t4[1408 + tid] = Y4[tid];
    }
    __syncthreads();

    int wave = tid >> 6;
    int lane = tid & 63;
    const float4* t4 = (const float4*)tab;

    if (wave == 0 || wave == 1) {
        int tbase = (wave == 0) ? 0 : 768;
        size_t obase = (wave == 0) ? (size_t)(OUT_A / 4) : (size_t)(OUT_Q / 4);
        float4 wreg[8];
#pragma unroll
        for (int k = 0; k < 8; ++k) wreg[k] = t4[tbase + k * 64 + lane];
        for (int bt = 0; bt < 64; ++bt) {
            float4 ya = t4[1408 + bt * 2];
            float4 yb = t4[1408 + bt * 2 + 1];
            float yk[8] = {ya.x, ya.y, ya.z, ya.w, yb.x, yb.y, yb.z, yb.w};
            float4 v = make_float4(0.f, 0.f, 0.f, 0.f);
#pragma unroll
            for (int k = 0; k < 8; ++k) {
                v.x = fmaf(yk[k], wreg[k].x, v.x);
                v.y = fmaf(yk[k], wreg[k].y, v.y);
                v.z = fmaf(yk[k], wreg[k].z, v.z);
                v.w = fmaf(yk[k], wreg[k].w, v.w);
            }
            out4[obase + (size_t)(bt0 + bt) * 64 + lane] = v;
        }
    } else if (wave == 2) {
        if (lane < 32) {
            float4 wreg[8];
#pragma unroll
            for (int k = 0; k < 8; ++k) wreg[k] = t4[512 + k * 32 + lane];
            for (int bt = 0; bt < 64; ++bt) {
                float4 ya = t4[1408 + bt * 2];
                float4 yb = t4[1408 + bt * 2 + 1];
                float yk[8] = {ya.x, ya.y, ya.z, ya.w, yb.x, yb.y, yb.z, yb.w};
                float4 v = make_float4(0.f, 0.f, 0.f, 0.f);
#pragma unroll
                for (int k = 0; k < 8; ++k) {
                    v.x = fmaf(yk[k], wreg[k].x, v.x);
                    v.y = fmaf(yk[k], wreg[k].y, v.y);
                    v.z = fmaf(yk[k], wreg[k].z, v.z);
                    v.w = fmaf(yk[k], wreg[k].w, v.w);
                }
                out4[(size_t)(OUT_B / 4) + (size_t)(bt0 + bt) * 32 + lane] = v;
            }
        } else {
            float4 c0 = t4[1280 + (lane - 32)];
            for (int bt = 0; bt < 64; ++bt)
                out4[(size_t)(OUT_C / 4) + (size_t)(bt0 + bt) * 128 + (lane - 32)] = c0;
        }
    } else {
        float4 c1 = t4[1280 + 32 + lane];
        float4 c2 = (lane < 32) ? t4[1280 + 96 + lane] : make_float4(0.f, 0.f, 0.f, 0.f);
        for (int bt = 0; bt < 64; ++bt) {
            out4[(size_t)(OUT_C / 4) + (size_t)(bt0 + bt) * 128 + 32 + lane] = c1;
            if (lane < 32)
                out4[(size_t)(OUT_C / 4) + (size_t)(bt0 + bt) * 128 + 96 + lane] = c2;
        }
    }
}

extern "C" void kernel_launch(void* const* d_in, const int* in_sizes, int n_in,
                              void* d_out, int out_size, void* d_ws, size_t ws_size,
                              hipStream_t stream) {
    const float* a_seq = (const float*)d_in[0];
    const float* A     = (const float*)d_in[1];
    const float* Bmat  = (const float*)d_in[2];
    const float* C     = (const float*)d_in[3];
    const float* Q     = (const float*)d_in[4];
    const float* wih_f = (const float*)d_in[5];
    const float* whh_f = (const float*)d_in[6];
    const float* bih_f = (const float*)d_in[7];
    const float* bhh_f = (const float*)d_in[8];
    const float* wih_b = (const float*)d_in[9];
    const float* whh_b = (const float*)d_in[10];
    const float* bih_b = (const float*)d_in[11];
    const float* bhh_b = (const float*)d_in[12];
    const float* wl    = (const float*)d_in[13];
    const float* bl    = (const float*)d_in[14];
    const float* wi    = (const float*)d_in[15];
    const float* bi    = (const float*)d_in[16];
    const float* u0    = (const float*)d_in[17];
    const float* useq  = (const float*)d_in[18];

    float* ws = (float*)d_ws;
    float* gx     = ws + WS_GX;
    float* hseq   = ws + WS_HSEQ;
    float* logits = ws + WS_LOGITS;   // aliases gx dir=0 half (written after GRU)
    float* initl  = ws + WS_INIT;
    float* yseq   = ws + WS_YSEQ;
    float* gs2    = ws + WS_YSEQ + (size_t)B * T * KK;  // after yseq (pre-GRU write)

    float* outf = (float*)d_out;
    float* logq = outf + OUT_LQ;
    float* logp = outf + OUT_LP;

    gx_kernel<<<1024 + (T * B * KK + 191) / 192, 192, 0, stream>>>(
        a_seq, wih_f, bih_f, wih_b, bih_b, gx, u0, useq, gs2);
    gru_kernel<<<256, 64, 0, stream>>>(gx, whh_f, bhh_f, whh_b, bhh_b, hseq);
    logits_kernel<<<T * B / 4, 256, 0, stream>>>(hseq, wl, bl, wi, bi, logits, initl);
    scan_kernel<<<4, 128, 0, stream>>>(logits, initl, gs2, yseq);
    lqlp_kernel<<<B * T * KK / 256, 256, 0, stream>>>(logits, initl, yseq, logq, logp);
    out_kernel<<<B * T / 64, 256, 0, stream>>>(yseq, A, Bmat, C, Q, (float4*)d_out);
}

// Round 18
// 444.387 us; speedup vs baseline: 1.4827x; 1.0227x over previous
//
#include <hip/hip_runtime.h>
#include <math.h>

#define T 512
#define B 128
#define KK 8
#define HH 32
#define PP 32

// ws layout (floats)
#define WS_GX    0             /* gx [dir*B+b][t][96] = 12582912 floats */
#define WS_HSEQ  12582912
#define WS_LOGITS 0            /* alias gx dir=0 half: scaled logits [t][b][64], written after GRU */
#define WS_INIT  16777216
#define WS_YSEQ  16778240

// d_out layout (floats)
#define OUT_A    0
#define OUT_B    16777216
#define OUT_C    25165824
#define OUT_Q    58720256
#define OUT_LQ   75497472
#define OUT_LP   75563008

#define TINV 2.0f
#define PSTAY 0.9f
#define OFFV (0.1f / 7.0f)
#define DPS (PSTAY - OFFV)
#define LOG_INV_K (-2.0794415416798357f)

typedef float f4v __attribute__((ext_vector_type(4)));
typedef __attribute__((address_space(3))) float as3f;

// async DMA global->LDS, 16B/lane, opaque to compiler (no auto waitcnt insertion)
__device__ __forceinline__ void dma16(unsigned ldsbyte, int voffbyte, const void* sbase) {
    asm volatile("s_mov_b32 m0, %0\n\t"
                 "global_load_lds_dwordx4 %1, %2"
                 :: "s"(ldsbyte), "v"(voffbyte), "s"(sbase)
                 : "memory");
}
// stores kept in asm: compiler does not track them -> no per-iter vmcnt drains
__device__ __forceinline__ void st16(void* p, f4v v) {
    asm volatile("global_store_dwordx4 %0, %1, off" :: "v"(p), "v"(v) : "memory");
}
// pinned LDS read: output lives in registers, cannot be rematerialized at use
__device__ __forceinline__ f4v ldsr16(int addr) {
    f4v out;
    asm volatile("ds_read_b128 %0, %1" : "=v"(out) : "v"(addr));
    return out;
}
// pinned global loads: outputs live in registers; caller does counted vmcnt
__device__ __forceinline__ f4v ldg16(const void* p) {
    f4v out;
    asm volatile("global_load_dwordx4 %0, %1, off" : "=v"(out) : "v"(p) : "memory");
    return out;
}
__device__ __forceinline__ float ldg4(const void* p) {
    float out;
    asm volatile("global_load_dword %0, %1, off" : "=v"(out) : "v"(p) : "memory");
    return out;
}

// ---------------- Kernel A: gx tiled + gsc folded in as extra blocks --------
__global__ __launch_bounds__(192) void gx_kernel(
    const float* __restrict__ a_seq,
    const float* __restrict__ wih_f, const float* __restrict__ bih_f,
    const float* __restrict__ wih_b, const float* __restrict__ bih_b,
    float* __restrict__ gx,
    const float* __restrict__ u0, const float* __restrict__ useq,
    float* __restrict__ gs) {
    __shared__ float xt[64 * 32];
    if (blockIdx.x >= 1024) {
        int id = (blockIdx.x - 1024) * 192 + threadIdx.x;
        if (id < T * B * KK) {
            int j = id & 7;
            int b = (id >> 3) & 127;
            int t = id >> 10;
            float u = (t == 0) ? u0[b * 8 + j]
                               : useq[((size_t)b * (T - 1) + (t - 1)) * 8 + j];
            gs[id] = -logf(-logf(u)) * TINV;   // precise logf (u near 1 ill-conditioned)
        }
        return;
    }
    int blk = blockIdx.x;
    int b = blk >> 3;
    int t0 = (blk & 7) << 6;
    int g = threadIdx.x;            // 0..191
    int dir = (g >= 96) ? 1 : 0;
    int gg = dir ? (g - 96) : g;
    const float* w = dir ? wih_b : wih_f;
    const float* bv = dir ? bih_b : bih_f;

    {
        const float4* src = (const float4*)(a_seq + ((size_t)b * T + t0) * PP);
        float4* dst = (float4*)xt;
        for (int idx = g; idx < 512; idx += 192) dst[idx] = src[idx];
    }
    float wreg[32];
#pragma unroll
    for (int q = 0; q < 8; ++q) {
        float4 wv = *(const float4*)(w + (size_t)gg * PP + q * 4);
        wreg[q * 4 + 0] = wv.x; wreg[q * 4 + 1] = wv.y;
        wreg[q * 4 + 2] = wv.z; wreg[q * 4 + 3] = wv.w;
    }
    float bias = bv[gg];
    __syncthreads();

    float* op = gx + ((size_t)(dir * B + b) * T + t0) * 96 + gg;
#pragma unroll 4
    for (int r = 0; r < 64; ++r) {
        const float4* xr = (const float4*)(xt + r * 32);
        float acc = bias;
#pragma unroll
        for (int q = 0; q < 8; ++q) {
            float4 xv = xr[q];
            acc = fmaf(xv.x, wreg[q * 4 + 0], acc);
            acc = fmaf(xv.y, wreg[q * 4 + 1], acc);
            acc = fmaf(xv.z, wreg[q * 4 + 2], acc);
            acc = fmaf(xv.w, wreg[q * 4 + 3], acc);
        }
        op[(size_t)r * 96] = acc;
    }
}

// ---------------- Kernel B: GRU scan, split accumulator chains (r17) --------
__global__ __launch_bounds__(64, 1) void gru_kernel(
    const float* __restrict__ gx,
    const float* __restrict__ whh_f, const float* __restrict__ bhh_f,
    const float* __restrict__ whh_b, const float* __restrict__ bhh_b,
    float* __restrict__ hseq) {
    int cid = blockIdx.x;            // 0..255 = dir*128 + b
    int b = cid & 127;
    int dir = cid >> 7;
    int i = threadIdx.x & 31;
    const float* whh = dir ? whh_b : whh_f;
    const float* bhh = dir ? bhh_b : bhh_f;
    const float* gp0 = gx + (size_t)cid * (T * 96);

    f4v wr[8], wz[8], wn[8];
#pragma unroll
    for (int q = 0; q < 8; ++q) {
        wr[q] = ldg16(whh + (size_t)i * 32 + q * 4);
        wz[q] = ldg16(whh + (size_t)(32 + i) * 32 + q * 4);
        wn[q] = ldg16(whh + (size_t)(64 + i) * 32 + q * 4);
    }
    float bhr = ldg4(bhh + i);
    float bhz = ldg4(bhh + 32 + i);
    float bhn = ldg4(bhh + 64 + i);

    const float* p = gp0 + (dir ? (T - 1) * 96 : 0);
    int gstep = dir ? -96 : 96;
    int voff = (((dir ? (T - 1) : 0) * B + b) * 64 + dir * 32 + i) * 4;
    int vstep = dir ? -(B * 64 * 4) : (B * 64 * 4);

    float pxrA[8], pxzA[8], pxnA[8], pxrB[8], pxzB[8], pxnB[8];

#define LOADG(PR, PZ, PN, G0) do {                                             \
        _Pragma("unroll")                                                      \
        for (int u_ = 0; u_ < 8; ++u_) {                                       \
            int sc_ = (G0) * 8 + u_; if (sc_ > T - 1) sc_ = T - 1;             \
            const float* rp_ = p + sc_ * gstep;                                \
            PR[u_] = ldg4(rp_ + i);                                            \
            PZ[u_] = ldg4(rp_ + 32 + i);                                       \
            PN[u_] = ldg4(rp_ + 64 + i);                                       \
        }                                                                      \
    } while (0)

#define GWAIT(N) do {                                                          \
        asm volatile("s_waitcnt vmcnt(" #N ")" ::: "memory");                  \
        __builtin_amdgcn_sched_barrier(0);                                     \
    } while (0)

#define GSTEP(PR, PZ, PN, SLOT) do {                                           \
        float hj_[32];                                                         \
        _Pragma("unroll")                                                      \
        for (int jj = 0; jj < 32; ++jj)                                        \
            hj_[jj] = __uint_as_float(                                         \
                __builtin_amdgcn_readlane(__float_as_uint(h), jj));            \
        __builtin_amdgcn_sched_barrier(0);                                     \
        float r0_ = PR[SLOT] + bhr, r1_ = 0.f, r2_ = 0.f, r3_ = 0.f;           \
        float z0_ = PZ[SLOT] + bhz, z1_ = 0.f, z2_ = 0.f, z3_ = 0.f;           \
        float n0_ = bhn, n1_ = 0.f, n2_ = 0.f, n3_ = 0.f;                      \
        _Pragma("unroll")                                                      \
        for (int q_ = 0; q_ < 2; ++q_) {                                       \
            _Pragma("unroll")                                                  \
            for (int c_ = 0; c_ < 4; ++c_) {                                   \
                float hv_ = hj_[q_ * 4 + c_];                                  \
                r0_ = fmaf(wr[q_][c_], hv_, r0_);                              \
                z0_ = fmaf(wz[q_][c_], hv_, z0_);                              \
                n0_ = fmaf(wn[q_][c_], hv_, n0_);                              \
            }                                                                  \
        }                                                                      \
        _Pragma("unroll")                                                      \
        for (int q_ = 2; q_ < 4; ++q_) {                                       \
            _Pragma("unroll")                                                  \
            for (int c_ = 0; c_ < 4; ++c_) {                                   \
                float hv_ = hj_[q_ * 4 + c_];                                  \
                r1_ = fmaf(wr[q_][c_], hv_, r1_);                              \
                z1_ = fmaf(wz[q_][c_], hv_, z1_);                              \
                n1_ = fmaf(wn[q_][c_], hv_, n1_);                              \
            }                                                                  \
        }                                                                      \
        _Pragma("unroll")                                                      \
        for (int q_ = 4; q_ < 6; ++q_) {                                       \
            _Pragma("unroll")                                                  \
            for (int c_ = 0; c_ < 4; ++c_) {                                   \
                float hv_ = hj_[q_ * 4 + c_];                                  \
                r2_ = fmaf(wr[q_][c_], hv_, r2_);                              \
                z2_ = fmaf(wz[q_][c_], hv_, z2_);                              \
                n2_ = fmaf(wn[q_][c_], hv_, n2_);                              \
            }                                                                  \
        }                                                                      \
        _Pragma("unroll")                                                      \
        for (int q_ = 6; q_ < 8; ++q_) {                                       \
            _Pragma("unroll")                                                  \
            for (int c_ = 0; c_ < 4; ++c_) {                                   \
                float hv_ = hj_[q_ * 4 + c_];                                  \
                r3_ = fmaf(wr[q_][c_], hv_, r3_);                              \
                z3_ = fmaf(wz[q_][c_], hv_, z3_);                              \
                n3_ = fmaf(wn[q_][c_], hv_, n3_);                              \
            }                                                                  \
        }                                                                      \
        float hr_ = (r0_ + r1_) + (r2_ + r3_);                                 \
        float hz_ = (z0_ + z1_) + (z2_ + z3_);                                 \
        float hn_ = (n0_ + n1_) + (n2_ + n3_);                                 \
        float r_ = __builtin_amdgcn_rcpf(1.f + __expf(-hr_));                  \
        float z_ = __builtin_amdgcn_rcpf(1.f + __expf(-hz_));                  \
        float na_ = fmaf(r_, hn_, PN[SLOT]);                                   \
        float e2_ = __expf(-2.f * fabsf(na_));                                 \
        float n_ = copysignf((1.f - e2_) * __builtin_amdgcn_rcpf(1.f + e2_), na_); \
        h = fmaf(z_, h - n_, n_);                                              \
        asm volatile("global_store_dword %0, %1, %2"                           \
                     :: "v"(voff), "v"(h), "s"(hseq) : "memory");              \
        voff += vstep;                                                         \
    } while (0)

    LOADG(pxrA, pxzA, pxnA, 0);
    GWAIT(0);
    float h = 0.f;

    for (int gq = 0; gq < 32; ++gq) {
        LOADG(pxrB, pxzB, pxnB, 2 * gq + 1);
        GWAIT(32);
        GSTEP(pxrA, pxzA, pxnA, 0); GSTEP(pxrA, pxzA, pxnA, 1);
        GSTEP(pxrA, pxzA, pxnA, 2); GSTEP(pxrA, pxzA, pxnA, 3);
        GSTEP(pxrA, pxzA, pxnA, 4); GSTEP(pxrA, pxzA, pxnA, 5);
        GSTEP(pxrA, pxzA, pxnA, 6); GSTEP(pxrA, pxzA, pxnA, 7);
        LOADG(pxrA, pxzA, pxnA, 2 * gq + 2);
        GWAIT(32);
        GSTEP(pxrB, pxzB, pxnB, 0); GSTEP(pxrB, pxzB, pxnB, 1);
        GSTEP(pxrB, pxzB, pxnB, 2); GSTEP(pxrB, pxzB, pxnB, 3);
        GSTEP(pxrB, pxzB, pxnB, 4); GSTEP(pxrB, pxzB, pxnB, 5);
        GSTEP(pxrB, pxzB, pxnB, 6); GSTEP(pxrB, pxzB, pxnB, 7);
    }
#undef LOADG
#undef GWAIT
#undef GSTEP
}

// ---------------- Kernel C: logits (round-13 LDS-staged, unchanged) ---------
__global__ __launch_bounds__(256) void logits_kernel(
    const float* __restrict__ hseq,
    const float* __restrict__ wl, const float* __restrict__ bl,
    const float* __restrict__ wi, const float* __restrict__ bi,
    float* __restrict__ logits, float* __restrict__ initl) {
    __shared__ float wls[64 * 65];
    __shared__ float hrow[4][64];
    int tid = threadIdx.x;
    for (int i2 = tid; i2 < 1024; i2 += 256) {
        float4 v = ((const float4*)wl)[i2];
        int gr = i2 >> 4;
        int cc = (i2 & 15) * 4;
        float* d = &wls[gr * 65 + cc];
        d[0] = v.x; d[1] = v.y; d[2] = v.z; d[3] = v.w;
    }
    int q = tid >> 6;
    int tb = blockIdx.x * 4 + q;   // t*B + b
    int g = tid & 63;
    hrow[q][g] = hseq[(size_t)tb * 64 + g];
    __syncthreads();
    float acc = bl[g];
    const float* wrow = &wls[g * 65];
#pragma unroll
    for (int c = 0; c < 64; ++c) acc = fmaf(wrow[c], hrow[q][c], acc);
    logits[(size_t)tb * 64 + g] = acc * TINV;
    if (tb < B && g < 8) {
        float a2 = bi[g];
        const float* w2 = wi + (size_t)g * 64;
#pragma unroll
        for (int c = 0; c < 64; ++c) a2 = fmaf(w2[c], hrow[q][c], a2);
        initl[tb * 8 + g] = a2;
    }
}

// ---------------- Kernel D: scan (r13 core) + C-broadcast on idle CUs -------
// blocks 0..3: the known-good producer/consumer scan (183 us, unchanged).
// blocks 4..2047: grid-stride broadcast of C[0] into out's C region (128 MiB
// of input-independent writes) — runs on otherwise-idle CUs, hidden under
// the scan. No LDS/barrier use in these blocks.
__global__ __launch_bounds__(128, 1) void scan_kernel(
    const float* __restrict__ logits, const float* __restrict__ initl,
    const float* __restrict__ gs, float* __restrict__ yseq,
    const float4* __restrict__ Csrc, float4* __restrict__ outC) {
    __shared__ float lds[6][2304];   // 6 slots x (32*64 logits + 32*8 gs)
    int tid = threadIdx.x;
    if (blockIdx.x >= 4) {
        // ---------------- C-broadcast blocks ----------------
        size_t stride = (size_t)(2048 - 4) * 128;
        for (size_t idx = (size_t)(blockIdx.x - 4) * 128 + tid;
             idx < (size_t)B * T * 128; idx += stride) {
            outC[idx] = Csrc[idx & 127];
        }
        return;
    }
    int wave = tid >> 6;
    int r = tid & 63;
    int b0 = blockIdx.x * 32;
    int b = b0 + (r & 31);
    int k15 = r & 15;

    unsigned ldsU = (unsigned)(unsigned long long)(as3f*)(&lds[0][0]);

#define ISSUE(tt, sl) do {                                                   \
        unsigned lb_ = ldsU + (unsigned)((sl) * 9216);                       \
        const char* bt_ = (const char*)logits + (size_t)(tt) * 32768;        \
        const char* gt_ = (const char*)gs + (size_t)(tt) * 4096;             \
        dma16(lb_ + 0 * 1024u, lof[0], bt_);                                 \
        dma16(lb_ + 1 * 1024u, lof[1], bt_);                                 \
        dma16(lb_ + 2 * 1024u, lof[2], bt_);                                 \
        dma16(lb_ + 3 * 1024u, lof[3], bt_);                                 \
        dma16(lb_ + 4 * 1024u, lof[4], bt_);                                 \
        dma16(lb_ + 5 * 1024u, lof[5], bt_);                                 \
        dma16(lb_ + 6 * 1024u, lof[6], bt_);                                 \
        dma16(lb_ + 7 * 1024u, lof[7], bt_);                                 \
        dma16(lb_ + 8192u, gof, gt_);                                        \
    } while (0)

    if (wave == 1) {
        // ---------------- DMA producer wave ----------------
        int lof[8];
#pragma unroll
        for (int q = 0; q < 8; ++q) {
            int rr = q * 4 + (r >> 4);         // tile row 0..31
            int cc = r & 15;                   // linear f4v col in LDS
            lof[q] = (((b0 + rr) * 64) + ((cc ^ (rr & 15)) << 2)) << 2;
        }
        int gof;
        {
            int rg = r >> 1;
            int cc = r & 1;
            gof = (((b0 + rg) * 8) + ((cc ^ (rg & 1)) << 2)) << 2;
        }
#pragma unroll
        for (int p = 1; p <= 5; ++p) ISSUE(p, p);
        asm volatile("s_waitcnt vmcnt(36)" ::: "memory");   // slot 1 landed
        __builtin_amdgcn_s_barrier();                        // #0
        for (int t = 1; t < T; ++t) {
            asm volatile("s_waitcnt vmcnt(27)" ::: "memory"); // slot t+1 landed
            __builtin_amdgcn_s_barrier();                     // #t
            int tp = t + 5; if (tp > T - 1) tp = T - 1;
            ISSUE(tp, (t + 5) % 6);
        }
        return;
    }

    // ---------------- compute consumer wave ----------------
    unsigned rbase = ldsU + (unsigned)((r & 31) * 256);
    unsigned gbase = ldsU + 8192u + (unsigned)((r & 31) * 32);

#define SREAD(LL, GA, GB, tt) do {                                           \
        int so_ = ((tt) % 6) * 9216;                                         \
        _Pragma("unroll")                                                    \
        for (int m_ = 0; m_ < 16; ++m_)                                      \
            LL[m_] = ldsr16((int)(rbase + so_ + ((m_ ^ k15) << 4)));         \
        GA = ldsr16((int)(gbase + so_ + ((r & 1) << 4)));                    \
        GB = ldsr16((int)(gbase + so_ + (((r & 1) ^ 1) << 4)));              \
    } while (0)

#define LWAIT() do {                                                         \
        asm volatile("s_waitcnt lgkmcnt(0)" ::: "memory");                   \
        __builtin_amdgcn_sched_barrier(0);                                   \
    } while (0)

#define SCOMP(LL, GA, GB, tt) do {                                           \
        float pl_[8];                                                        \
        _Pragma("unroll")                                                    \
        for (int j_ = 0; j_ < 8; ++j_) pl_[j_] = 0.f;                        \
        _Pragma("unroll")                                                    \
        for (int k_ = 0; k_ < 8; ++k_) {                                     \
            f4v w0_ = LL[2 * k_], w1_ = LL[2 * k_ + 1];                      \
            float ek_ = e[k_];                                               \
            pl_[0] = fmaf(ek_, w0_.x, pl_[0]); pl_[1] = fmaf(ek_, w0_.y, pl_[1]); \
            pl_[2] = fmaf(ek_, w0_.z, pl_[2]); pl_[3] = fmaf(ek_, w0_.w, pl_[3]); \
            pl_[4] = fmaf(ek_, w1_.x, pl_[4]); pl_[5] = fmaf(ek_, w1_.y, pl_[5]); \
            pl_[6] = fmaf(ek_, w1_.z, pl_[6]); pl_[7] = fmaf(ek_, w1_.w, pl_[7]); \
        }                                                                    \
        float gg_[8] = {GA.x, GA.y, GA.z, GA.w, GB.x, GB.y, GB.z, GB.w};     \
        float ss_ = 0.f;                                                     \
        _Pragma("unroll")                                                    \
        for (int j_ = 0; j_ < 8; ++j_) {                                     \
            float a_ = fmaf(pl_[j_], sinv, gg_[j_]);                         \
            e[j_] = __expf(a_);                                              \
            ss_ += e[j_];                                                    \
        }                                                                    \
        sinv = __builtin_amdgcn_rcpf(ss_);                                   \
        if (r < 32) {                                                        \
            f4v v0_ = (f4v){e[0] * sinv, e[1] * sinv, e[2] * sinv, e[3] * sinv}; \
            f4v v1_ = (f4v){e[4] * sinv, e[5] * sinv, e[6] * sinv, e[7] * sinv}; \
            st16(&yp[2 * (tt)], v0_);                                        \
            st16(&yp[2 * (tt) + 1], v1_);                                    \
        }                                                                    \
    } while (0)

    f4v* yp = (f4v*)(yseq + (size_t)b * T * 8);
    float e[8];
    float sinv;

    // ---- t = 0 from initl + gs[0] (plain loads, compiler-tracked) ----
    {
        const f4v* il4 = (const f4v*)(initl + b * 8);
        f4v i0 = il4[0], i1 = il4[1];
        const f4v* g4 = (const f4v*)(gs + b * 8);
        f4v G0 = g4[0], G1 = g4[1];
        float a[8];
        a[0] = fmaf(i0.x, TINV, G0.x); a[1] = fmaf(i0.y, TINV, G0.y);
        a[2] = fmaf(i0.z, TINV, G0.z); a[3] = fmaf(i0.w, TINV, G0.w);
        a[4] = fmaf(i1.x, TINV, G1.x); a[5] = fmaf(i1.y, TINV, G1.y);
        a[6] = fmaf(i1.z, TINV, G1.z); a[7] = fmaf(i1.w, TINV, G1.w);
        float ssum = 0.f;
#pragma unroll
        for (int j = 0; j < 8; ++j) { e[j] = __expf(a[j]); ssum += e[j]; }
        sinv = __builtin_amdgcn_rcpf(ssum);
        if (r < 32) {
            f4v y0v = (f4v){e[0] * sinv, e[1] * sinv, e[2] * sinv, e[3] * sinv};
            f4v y1v = (f4v){e[4] * sinv, e[5] * sinv, e[6] * sinv, e[7] * sinv};
            st16(&yp[0], y0v);
            st16(&yp[1], y1v);
        }
    }

    f4v LA[16], LB[16], gaA, gbA, gaB, gbB;

    __builtin_amdgcn_s_barrier();      // #0: slot 1 landed (producer vmcnt(36))
    SREAD(LA, gaA, gbA, 1);

    for (int t = 1; t < T - 1; t += 2) {
        __builtin_amdgcn_s_barrier();  // #t: slot t+1 landed
        LWAIT();                       // prior phase's SREAD retired
        SREAD(LB, gaB, gbB, t + 1);
        SCOMP(LA, gaA, gbA, t);

        __builtin_amdgcn_s_barrier();  // #t+1: slot t+2 landed
        LWAIT();
        SREAD(LA, gaA, gbA, t + 2);
        SCOMP(LB, gaB, gbB, t + 1);
    }
    __builtin_amdgcn_s_barrier();      // #511
    LWAIT();
    SCOMP(LA, gaA, gbA, T - 1);
#undef ISSUE
#undef SREAD
#undef LWAIT
#undef SCOMP
}

// ---------------- Kernel E: log_q / log_p (round-14 version, unchanged) -----
__global__ __launch_bounds__(256) void lqlp_kernel(
    const float* __restrict__ logits, const float* __restrict__ initl,
    const float* __restrict__ yseq,
    float* __restrict__ logq, float* __restrict__ logp) {
    int tid = blockIdx.x * 256 + threadIdx.x;   // (b*T + t)*8 + j
    int j = tid & 7;
    int row = tid >> 3;                          // b*T + t
    int b = row >> 9;
    int t = row & (T - 1);

    const float4* yt4 = (const float4*)(yseq + (size_t)row * 8);
    float4 ya = yt4[0], yb = yt4[1];
    float yt[8] = {ya.x, ya.y, ya.z, ya.w, yb.x, yb.y, yb.z, yb.w};

    float l[8];
    float lp;
    if (t == 0) {
        const float4* il4 = (const float4*)(initl + b * 8);
        float4 i0 = il4[0], i1 = il4[1];
        l[0] = i0.x; l[1] = i0.y; l[2] = i0.z; l[3] = i0.w;
        l[4] = i1.x; l[5] = i1.y; l[6] = i1.z; l[7] = i1.w;
        float sy = ((yt[0] + yt[1]) + (yt[2] + yt[3])) + ((yt[4] + yt[5]) + (yt[6] + yt[7]));
        lp = LOG_INV_K * sy;
    } else {
        const float4* yp4 = (const float4*)(yseq + (size_t)row * 8 - 8);
        float4 p0 = yp4[0], p1 = yp4[1];
        float ypv[8] = {p0.x, p0.y, p0.z, p0.w, p1.x, p1.y, p1.z, p1.w};
        float ypj = yseq[(size_t)row * 8 - 8 + j];
        const float4* L4 = (const float4*)(logits + ((size_t)t * B + b) * 64 + j * 8);
        float4 r0 = L4[0], r1 = L4[1];
        float c[8] = {ypj * r0.x, ypj * r0.y, ypj * r0.z, ypj * r0.w,
                      ypj * r1.x, ypj * r1.y, ypj * r1.z, ypj * r1.w};
#pragma unroll
        for (int s = 1; s <= 4; s <<= 1) {
#pragma unroll
            for (int m = 0; m < 8; ++m) c[m] += __shfl_xor(c[m], s, 64);
        }
#pragma unroll
        for (int m = 0; m < 8; ++m) l[m] = c[m] * 0.5f;
        float sy = ((ypv[0] + ypv[1]) + (ypv[2] + ypv[3])) + ((ypv[4] + ypv[5]) + (ypv[6] + ypv[7]));
        float acc = 0.f;
#pragma unroll
        for (int m = 0; m < 8; ++m) {
            float tp = fmaf(DPS, ypv[m], OFFV * sy);
            acc = fmaf(yt[m], logf(fmaxf(tp, 1e-8f)), acc);
        }
        lp = acc;
    }
    float m = fmaxf(fmaxf(fmaxf(l[0], l[1]), fmaxf(l[2], l[3])),
                    fmaxf(fmaxf(l[4], l[5]), fmaxf(l[6], l[7])));
    float se = 0.f;
#pragma unroll
    for (int m2 = 0; m2 < 8; ++m2) se += __expf(l[m2] - m);
    float lse = m + logf(se);
    float lq = 0.f;
#pragma unroll
    for (int m2 = 0; m2 < 8; ++m2) lq = fmaf(yt[m2], l[m2] - lse, lq);
    if (j == 0) {
        logq[row] = lq;
        logp[row] = lp;
    }
}

// ---------------- Kernel F: output einsums, C region removed ----------------
__global__ __launch_bounds__(256) void out_kernel(
    const float* __restrict__ yseq,
    const float* __restrict__ A, const float* __restrict__ Bm,
    const float* __restrict__ Q,
    float4* __restrict__ out4) {
    __shared__ float tab[5632];      // A:0..2047  B:2048..3071  Q:3072..5119
                                     // Y:5120..5631
    int tid = threadIdx.x;
    int bt0 = blockIdx.x * 64;
    {
        float4* t4 = (float4*)tab;
        const float4* A4 = (const float4*)A;
        const float4* B4 = (const float4*)Bm;
        const float4* Q4 = (const float4*)Q;
        for (int i2 = tid; i2 < 512; i2 += 256) t4[i2] = A4[i2];
        if (tid < 256) t4[512 + tid] = B4[tid];
        for (int i2 = tid; i2 < 512; i2 += 256) t4[768 + i2] = Q4[i2];
        const float4* Y4 = (const float4*)(yseq + (size_t)bt0 * 8);
        if (tid < 128) t4[1280 + tid] = Y4[tid];
    }
    __syncthreads();

    int wave = tid >> 6;
    int lane = tid & 63;
    const float4* t4 = (const float4*)tab;

    if (wave == 0 || wave == 1) {
        int tbase = (wave == 0) ? 0 : 768;
        size_t obase = (wave == 0) ? (size_t)(OUT_A / 4) : (size_t)(OUT_Q / 4);
        float4 wreg[8];
#pragma unroll
        for (int k = 0; k < 8; ++k) wreg[k] = t4[tbase + k * 64 + lane];
        for (int bt = 0; bt < 64; ++bt) {
            float4 ya = t4[1280 + bt * 2];
            float4 yb = t4[1280 + bt * 2 + 1];
            float yk[8] = {ya.x, ya.y, ya.z, ya.w, yb.x, yb.y, yb.z, yb.w};
            float4 v = make_float4(0.f, 0.f, 0.f, 0.f);
#pragma unroll
            for (int k = 0; k < 8; ++k) {
                v.x = fmaf(yk[k], wreg[k].x, v.x);
                v.y = fmaf(yk[k], wreg[k].y, v.y);
                v.z = fmaf(yk[k], wreg[k].z, v.z);
                v.w = fmaf(yk[k], wreg[k].w, v.w);
            }
            out4[obase + (size_t)(bt0 + bt) * 64 + lane] = v;
        }
    } else if (wave == 2 && lane < 32) {
        float4 wreg[8];
#pragma unroll
        for (int k = 0; k < 8; ++k) wreg[k] = t4[512 + k * 32 + lane];
        for (int bt = 0; bt < 64; ++bt) {
            float4 ya = t4[1280 + bt * 2];
            float4 yb = t4[1280 + bt * 2 + 1];
            float yk[8] = {ya.x, ya.y, ya.z, ya.w, yb.x, yb.y, yb.z, yb.w};
            float4 v = make_float4(0.f, 0.f, 0.f, 0.f);
#pragma unroll
            for (int k = 0; k < 8; ++k) {
                v.x = fmaf(yk[k], wreg[k].x, v.x);
                v.y = fmaf(yk[k], wreg[k].y, v.y);
                v.z = fmaf(yk[k], wreg[k].z, v.z);
                v.w = fmaf(yk[k], wreg[k].w, v.w);
            }
            out4[(size_t)(OUT_B / 4) + (size_t)(bt0 + bt) * 32 + lane] = v;
        }
    }
}

extern "C" void kernel_launch(void* const* d_in, const int* in_sizes, int n_in,
                              void* d_out, int out_size, void* d_ws, size_t ws_size,
                              hipStream_t stream) {
    const float* a_seq = (const float*)d_in[0];
    const float* A     = (const float*)d_in[1];
    const float* Bmat  = (const float*)d_in[2];
    const float* C     = (const float*)d_in[3];
    const float* Q     = (const float*)d_in[4];
    const float* wih_f = (const float*)d_in[5];
    const float* whh_f = (const float*)d_in[6];
    const float* bih_f = (const float*)d_in[7];
    const float* bhh_f = (const float*)d_in[8];
    const float* wih_b = (const float*)d_in[9];
    const float* whh_b = (const float*)d_in[10];
    const float* bih_b = (const float*)d_in[11];
    const float* bhh_b = (const float*)d_in[12];
    const float* wl    = (const float*)d_in[13];
    const float* bl    = (const float*)d_in[14];
    const float* wi    = (const float*)d_in[15];
    const float* bi    = (const float*)d_in[16];
    const float* u0    = (const float*)d_in[17];
    const float* useq  = (const float*)d_in[18];

    float* ws = (float*)d_ws;
    float* gx     = ws + WS_GX;
    float* hseq   = ws + WS_HSEQ;
    float* logits = ws + WS_LOGITS;   // aliases gx dir=0 half (written after GRU)
    float* initl  = ws + WS_INIT;
    float* yseq   = ws + WS_YSEQ;
    float* gs2    = ws + WS_YSEQ + (size_t)B * T * KK;  // after yseq (pre-GRU write)

    float* outf = (float*)d_out;
    float* logq = outf + OUT_LQ;
    float* logp = outf + OUT_LP;
    float4* outC = (float4*)(outf + OUT_C);

    gx_kernel<<<1024 + (T * B * KK + 191) / 192, 192, 0, stream>>>(
        a_seq, wih_f, bih_f, wih_b, bih_b, gx, u0, useq, gs2);
    gru_kernel<<<256, 64, 0, stream>>>(gx, whh_f, bhh_f, whh_b, bhh_b, hseq);
    logits_kernel<<<T * B / 4, 256, 0, stream>>>(hseq, wl, bl, wi, bi, logits, initl);
    scan_kernel<<<2048, 128, 0, stream>>>(logits, initl, gs2, yseq,
                                          (const float4*)C, outC);
    lqlp_kernel<<<B * T * KK / 256, 256, 0, stream>>>(logits, initl, yseq, logq, logp);
    out_kernel<<<B * T / 64, 256, 0, stream>>>(yseq, A, Bmat, Q, (float4*)d_out);
}

// Round 19
// 439.375 us; speedup vs baseline: 1.4996x; 1.0114x over previous
//
#include <hip/hip_runtime.h>
#include <math.h>

#define T 512
#define B 128
#define KK 8
#define HH 32
#define PP 32

// ws layout (floats)
#define WS_GX    0             /* gx [dir*B+b][t][96] = 12582912 floats */
#define WS_HSEQ  12582912
#define WS_LOGITS 0            /* alias gx dir=0 half: scaled logits [t][b][64], written after GRU */
#define WS_INIT  16777216
#define WS_YSEQ  16778240

// d_out layout (floats)
#define OUT_A    0
#define OUT_B    16777216
#define OUT_C    25165824
#define OUT_Q    58720256
#define OUT_LQ   75497472
#define OUT_LP   75563008

#define TINV 2.0f
#define PSTAY 0.9f
#define OFFV (0.1f / 7.0f)
#define DPS (PSTAY - OFFV)
#define LOG_INV_K (-2.0794415416798357f)

typedef float f4v __attribute__((ext_vector_type(4)));
typedef __attribute__((address_space(3))) float as3f;

// async DMA global->LDS, 16B/lane, opaque to compiler (no auto waitcnt insertion)
__device__ __forceinline__ void dma16(unsigned ldsbyte, int voffbyte, const void* sbase) {
    asm volatile("s_mov_b32 m0, %0\n\t"
                 "global_load_lds_dwordx4 %1, %2"
                 :: "s"(ldsbyte), "v"(voffbyte), "s"(sbase)
                 : "memory");
}
// stores kept in asm: compiler does not track them -> no per-iter vmcnt drains
__device__ __forceinline__ void st16(void* p, f4v v) {
    asm volatile("global_store_dwordx4 %0, %1, off" :: "v"(p), "v"(v) : "memory");
}
// pinned LDS read: output lives in registers, cannot be rematerialized at use
__device__ __forceinline__ f4v ldsr16(int addr) {
    f4v out;
    asm volatile("ds_read_b128 %0, %1" : "=v"(out) : "v"(addr));
    return out;
}
// pinned global loads: outputs live in registers; caller does counted vmcnt
__device__ __forceinline__ f4v ldg16(const void* p) {
    f4v out;
    asm volatile("global_load_dwordx4 %0, %1, off" : "=v"(out) : "v"(p) : "memory");
    return out;
}
__device__ __forceinline__ float ldg4(const void* p) {
    float out;
    asm volatile("global_load_dword %0, %1, off" : "=v"(out) : "v"(p) : "memory");
    return out;
}

// ---------------- Kernel A: gx tiled + gsc folded in as extra blocks --------
__global__ __launch_bounds__(192) void gx_kernel(
    const float* __restrict__ a_seq,
    const float* __restrict__ wih_f, const float* __restrict__ bih_f,
    const float* __restrict__ wih_b, const float* __restrict__ bih_b,
    float* __restrict__ gx,
    const float* __restrict__ u0, const float* __restrict__ useq,
    float* __restrict__ gs) {
    __shared__ float xt[64 * 32];
    if (blockIdx.x >= 1024) {
        int id = (blockIdx.x - 1024) * 192 + threadIdx.x;
        if (id < T * B * KK) {
            int j = id & 7;
            int b = (id >> 3) & 127;
            int t = id >> 10;
            float u = (t == 0) ? u0[b * 8 + j]
                               : useq[((size_t)b * (T - 1) + (t - 1)) * 8 + j];
            gs[id] = -logf(-logf(u)) * TINV;   // precise logf (u near 1 ill-conditioned)
        }
        return;
    }
    int blk = blockIdx.x;
    int b = blk >> 3;
    int t0 = (blk & 7) << 6;
    int g = threadIdx.x;            // 0..191
    int dir = (g >= 96) ? 1 : 0;
    int gg = dir ? (g - 96) : g;
    const float* w = dir ? wih_b : wih_f;
    const float* bv = dir ? bih_b : bih_f;

    {
        const float4* src = (const float4*)(a_seq + ((size_t)b * T + t0) * PP);
        float4* dst = (float4*)xt;
        for (int idx = g; idx < 512; idx += 192) dst[idx] = src[idx];
    }
    float wreg[32];
#pragma unroll
    for (int q = 0; q < 8; ++q) {
        float4 wv = *(const float4*)(w + (size_t)gg * PP + q * 4);
        wreg[q * 4 + 0] = wv.x; wreg[q * 4 + 1] = wv.y;
        wreg[q * 4 + 2] = wv.z; wreg[q * 4 + 3] = wv.w;
    }
    float bias = bv[gg];
    __syncthreads();

    float* op = gx + ((size_t)(dir * B + b) * T + t0) * 96 + gg;
#pragma unroll 4
    for (int r = 0; r < 64; ++r) {
        const float4* xr = (const float4*)(xt + r * 32);
        float acc = bias;
#pragma unroll
        for (int q = 0; q < 8; ++q) {
            float4 xv = xr[q];
            acc = fmaf(xv.x, wreg[q * 4 + 0], acc);
            acc = fmaf(xv.y, wreg[q * 4 + 1], acc);
            acc = fmaf(xv.z, wreg[q * 4 + 2], acc);
            acc = fmaf(xv.w, wreg[q * 4 + 3], acc);
        }
        op[(size_t)r * 96] = acc;
    }
}

// ---------------- Kernel B: GRU scan, split accumulator chains (r17) --------
__global__ __launch_bounds__(64, 1) void gru_kernel(
    const float* __restrict__ gx,
    const float* __restrict__ whh_f, const float* __restrict__ bhh_f,
    const float* __restrict__ whh_b, const float* __restrict__ bhh_b,
    float* __restrict__ hseq) {
    int cid = blockIdx.x;            // 0..255 = dir*128 + b
    int b = cid & 127;
    int dir = cid >> 7;
    int i = threadIdx.x & 31;
    const float* whh = dir ? whh_b : whh_f;
    const float* bhh = dir ? bhh_b : bhh_f;
    const float* gp0 = gx + (size_t)cid * (T * 96);

    f4v wr[8], wz[8], wn[8];
#pragma unroll
    for (int q = 0; q < 8; ++q) {
        wr[q] = ldg16(whh + (size_t)i * 32 + q * 4);
        wz[q] = ldg16(whh + (size_t)(32 + i) * 32 + q * 4);
        wn[q] = ldg16(whh + (size_t)(64 + i) * 32 + q * 4);
    }
    float bhr = ldg4(bhh + i);
    float bhz = ldg4(bhh + 32 + i);
    float bhn = ldg4(bhh + 64 + i);

    const float* p = gp0 + (dir ? (T - 1) * 96 : 0);
    int gstep = dir ? -96 : 96;
    int voff = (((dir ? (T - 1) : 0) * B + b) * 64 + dir * 32 + i) * 4;
    int vstep = dir ? -(B * 64 * 4) : (B * 64 * 4);

    float pxrA[8], pxzA[8], pxnA[8], pxrB[8], pxzB[8], pxnB[8];

#define LOADG(PR, PZ, PN, G0) do {                                             \
        _Pragma("unroll")                                                      \
        for (int u_ = 0; u_ < 8; ++u_) {                                       \
            int sc_ = (G0) * 8 + u_; if (sc_ > T - 1) sc_ = T - 1;             \
            const float* rp_ = p + sc_ * gstep;                                \
            PR[u_] = ldg4(rp_ + i);                                            \
            PZ[u_] = ldg4(rp_ + 32 + i);                                       \
            PN[u_] = ldg4(rp_ + 64 + i);                                       \
        }                                                                      \
    } while (0)

#define GWAIT(N) do {                                                          \
        asm volatile("s_waitcnt vmcnt(" #N ")" ::: "memory");                  \
        __builtin_amdgcn_sched_barrier(0);                                     \
    } while (0)

#define GSTEP(PR, PZ, PN, SLOT) do {                                           \
        float hj_[32];                                                         \
        _Pragma("unroll")                                                      \
        for (int jj = 0; jj < 32; ++jj)                                        \
            hj_[jj] = __uint_as_float(                                         \
                __builtin_amdgcn_readlane(__float_as_uint(h), jj));            \
        __builtin_amdgcn_sched_barrier(0);                                     \
        float r0_ = PR[SLOT] + bhr, r1_ = 0.f, r2_ = 0.f, r3_ = 0.f;           \
        float z0_ = PZ[SLOT] + bhz, z1_ = 0.f, z2_ = 0.f, z3_ = 0.f;           \
        float n0_ = bhn, n1_ = 0.f, n2_ = 0.f, n3_ = 0.f;                      \
        _Pragma("unroll")                                                      \
        for (int q_ = 0; q_ < 2; ++q_) {                                       \
            _Pragma("unroll")                                                  \
            for (int c_ = 0; c_ < 4; ++c_) {                                   \
                float hv_ = hj_[q_ * 4 + c_];                                  \
                r0_ = fmaf(wr[q_][c_], hv_, r0_);                              \
                z0_ = fmaf(wz[q_][c_], hv_, z0_);                              \
                n0_ = fmaf(wn[q_][c_], hv_, n0_);                              \
            }                                                                  \
        }                                                                      \
        _Pragma("unroll")                                                      \
        for (int q_ = 2; q_ < 4; ++q_) {                                       \
            _Pragma("unroll")                                                  \
            for (int c_ = 0; c_ < 4; ++c_) {                                   \
                float hv_ = hj_[q_ * 4 + c_];                                  \
                r1_ = fmaf(wr[q_][c_], hv_, r1_);                              \
                z1_ = fmaf(wz[q_][c_], hv_, z1_);                              \
                n1_ = fmaf(wn[q_][c_], hv_, n1_);                              \
            }                                                                  \
        }                                                                      \
        _Pragma("unroll")                                                      \
        for (int q_ = 4; q_ < 6; ++q_) {                                       \
            _Pragma("unroll")                                                  \
            for (int c_ = 0; c_ < 4; ++c_) {                                   \
                float hv_ = hj_[q_ * 4 + c_];                                  \
                r2_ = fmaf(wr[q_][c_], hv_, r2_);                              \
                z2_ = fmaf(wz[q_][c_], hv_, z2_);                              \
                n2_ = fmaf(wn[q_][c_], hv_, n2_);                              \
            }                                                                  \
        }                                                                      \
        _Pragma("unroll")                                                      \
        for (int q_ = 6; q_ < 8; ++q_) {                                       \
            _Pragma("unroll")                                                  \
            for (int c_ = 0; c_ < 4; ++c_) {                                   \
                float hv_ = hj_[q_ * 4 + c_];                                  \
                r3_ = fmaf(wr[q_][c_], hv_, r3_);                              \
                z3_ = fmaf(wz[q_][c_], hv_, z3_);                              \
                n3_ = fmaf(wn[q_][c_], hv_, n3_);                              \
            }                                                                  \
        }                                                                      \
        float hr_ = (r0_ + r1_) + (r2_ + r3_);                                 \
        float hz_ = (z0_ + z1_) + (z2_ + z3_);                                 \
        float hn_ = (n0_ + n1_) + (n2_ + n3_);                                 \
        float r_ = __builtin_amdgcn_rcpf(1.f + __expf(-hr_));                  \
        float z_ = __builtin_amdgcn_rcpf(1.f + __expf(-hz_));                  \
        float na_ = fmaf(r_, hn_, PN[SLOT]);                                   \
        float e2_ = __expf(-2.f * fabsf(na_));                                 \
        float n_ = copysignf((1.f - e2_) * __builtin_amdgcn_rcpf(1.f + e2_), na_); \
        h = fmaf(z_, h - n_, n_);                                              \
        asm volatile("global_store_dword %0, %1, %2"                           \
                     :: "v"(voff), "v"(h), "s"(hseq) : "memory");              \
        voff += vstep;                                                         \
    } while (0)

    LOADG(pxrA, pxzA, pxnA, 0);
    GWAIT(0);
    float h = 0.f;

    for (int gq = 0; gq < 32; ++gq) {
        LOADG(pxrB, pxzB, pxnB, 2 * gq + 1);
        GWAIT(32);
        GSTEP(pxrA, pxzA, pxnA, 0); GSTEP(pxrA, pxzA, pxnA, 1);
        GSTEP(pxrA, pxzA, pxnA, 2); GSTEP(pxrA, pxzA, pxnA, 3);
        GSTEP(pxrA, pxzA, pxnA, 4); GSTEP(pxrA, pxzA, pxnA, 5);
        GSTEP(pxrA, pxzA, pxnA, 6); GSTEP(pxrA, pxzA, pxnA, 7);
        LOADG(pxrA, pxzA, pxnA, 2 * gq + 2);
        GWAIT(32);
        GSTEP(pxrB, pxzB, pxnB, 0); GSTEP(pxrB, pxzB, pxnB, 1);
        GSTEP(pxrB, pxzB, pxnB, 2); GSTEP(pxrB, pxzB, pxnB, 3);
        GSTEP(pxrB, pxzB, pxnB, 4); GSTEP(pxrB, pxzB, pxnB, 5);
        GSTEP(pxrB, pxzB, pxnB, 6); GSTEP(pxrB, pxzB, pxnB, 7);
    }
#undef LOADG
#undef GWAIT
#undef GSTEP
}

// ---------------- Kernel C: logits (round-13 LDS-staged, unchanged) ---------
__global__ __launch_bounds__(256) void logits_kernel(
    const float* __restrict__ hseq,
    const float* __restrict__ wl, const float* __restrict__ bl,
    const float* __restrict__ wi, const float* __restrict__ bi,
    float* __restrict__ logits, float* __restrict__ initl) {
    __shared__ float wls[64 * 65];
    __shared__ float hrow[4][64];
    int tid = threadIdx.x;
    for (int i2 = tid; i2 < 1024; i2 += 256) {
        float4 v = ((const float4*)wl)[i2];
        int gr = i2 >> 4;
        int cc = (i2 & 15) * 4;
        float* d = &wls[gr * 65 + cc];
        d[0] = v.x; d[1] = v.y; d[2] = v.z; d[3] = v.w;
    }
    int q = tid >> 6;
    int tb = blockIdx.x * 4 + q;   // t*B + b
    int g = tid & 63;
    hrow[q][g] = hseq[(size_t)tb * 64 + g];
    __syncthreads();
    float acc = bl[g];
    const float* wrow = &wls[g * 65];
#pragma unroll
    for (int c = 0; c < 64; ++c) acc = fmaf(wrow[c], hrow[q][c], acc);
    logits[(size_t)tb * 64 + g] = acc * TINV;
    if (tb < B && g < 8) {
        float a2 = bi[g];
        const float* w2 = wi + (size_t)g * 64;
#pragma unroll
        for (int c = 0; c < 64; ++c) a2 = fmaf(w2[c], hrow[q][c], a2);
        initl[tb * 8 + g] = a2;
    }
}

// ---------------- Kernel D: scan (r13 core) + C-broadcast on idle CUs -------
__global__ __launch_bounds__(128, 1) void scan_kernel(
    const float* __restrict__ logits, const float* __restrict__ initl,
    const float* __restrict__ gs, float* __restrict__ yseq,
    const float4* __restrict__ Csrc, float4* __restrict__ outC) {
    __shared__ float lds[6][2304];   // 6 slots x (32*64 logits + 32*8 gs)
    int tid = threadIdx.x;
    if (blockIdx.x >= 4) {
        // ---------------- C-broadcast blocks ----------------
        size_t stride = (size_t)(2048 - 4) * 128;
        for (size_t idx = (size_t)(blockIdx.x - 4) * 128 + tid;
             idx < (size_t)B * T * 128; idx += stride) {
            outC[idx] = Csrc[idx & 127];
        }
        return;
    }
    int wave = tid >> 6;
    int r = tid & 63;
    int b0 = blockIdx.x * 32;
    int b = b0 + (r & 31);
    int k15 = r & 15;

    unsigned ldsU = (unsigned)(unsigned long long)(as3f*)(&lds[0][0]);

#define ISSUE(tt, sl) do {                                                   \
        unsigned lb_ = ldsU + (unsigned)((sl) * 9216);                       \
        const char* bt_ = (const char*)logits + (size_t)(tt) * 32768;        \
        const char* gt_ = (const char*)gs + (size_t)(tt) * 4096;             \
        dma16(lb_ + 0 * 1024u, lof[0], bt_);                                 \
        dma16(lb_ + 1 * 1024u, lof[1], bt_);                                 \
        dma16(lb_ + 2 * 1024u, lof[2], bt_);                                 \
        dma16(lb_ + 3 * 1024u, lof[3], bt_);                                 \
        dma16(lb_ + 4 * 1024u, lof[4], bt_);                                 \
        dma16(lb_ + 5 * 1024u, lof[5], bt_);                                 \
        dma16(lb_ + 6 * 1024u, lof[6], bt_);                                 \
        dma16(lb_ + 7 * 1024u, lof[7], bt_);                                 \
        dma16(lb_ + 8192u, gof, gt_);                                        \
    } while (0)

    if (wave == 1) {
        // ---------------- DMA producer wave ----------------
        int lof[8];
#pragma unroll
        for (int q = 0; q < 8; ++q) {
            int rr = q * 4 + (r >> 4);         // tile row 0..31
            int cc = r & 15;                   // linear f4v col in LDS
            lof[q] = (((b0 + rr) * 64) + ((cc ^ (rr & 15)) << 2)) << 2;
        }
        int gof;
        {
            int rg = r >> 1;
            int cc = r & 1;
            gof = (((b0 + rg) * 8) + ((cc ^ (rg & 1)) << 2)) << 2;
        }
#pragma unroll
        for (int p = 1; p <= 5; ++p) ISSUE(p, p);
        asm volatile("s_waitcnt vmcnt(36)" ::: "memory");   // slot 1 landed
        __builtin_amdgcn_s_barrier();                        // #0
        for (int t = 1; t < T; ++t) {
            asm volatile("s_waitcnt vmcnt(27)" ::: "memory"); // slot t+1 landed
            __builtin_amdgcn_s_barrier();                     // #t
            int tp = t + 5; if (tp > T - 1) tp = T - 1;
            ISSUE(tp, (t + 5) % 6);
        }
        return;
    }

    // ---------------- compute consumer wave ----------------
    unsigned rbase = ldsU + (unsigned)((r & 31) * 256);
    unsigned gbase = ldsU + 8192u + (unsigned)((r & 31) * 32);

#define SREAD(LL, GA, GB, tt) do {                                           \
        int so_ = ((tt) % 6) * 9216;                                         \
        _Pragma("unroll")                                                    \
        for (int m_ = 0; m_ < 16; ++m_)                                      \
            LL[m_] = ldsr16((int)(rbase + so_ + ((m_ ^ k15) << 4)));         \
        GA = ldsr16((int)(gbase + so_ + ((r & 1) << 4)));                    \
        GB = ldsr16((int)(gbase + so_ + (((r & 1) ^ 1) << 4)));              \
    } while (0)

#define LWAIT() do {                                                         \
        asm volatile("s_waitcnt lgkmcnt(0)" ::: "memory");                   \
        __builtin_amdgcn_sched_barrier(0);                                   \
    } while (0)

#define SCOMP(LL, GA, GB, tt) do {                                           \
        float pl_[8];                                                        \
        _Pragma("unroll")                                                    \
        for (int j_ = 0; j_ < 8; ++j_) pl_[j_] = 0.f;                        \
        _Pragma("unroll")                                                    \
        for (int k_ = 0; k_ < 8; ++k_) {                                     \
            f4v w0_ = LL[2 * k_], w1_ = LL[2 * k_ + 1];                      \
            float ek_ = e[k_];                                               \
            pl_[0] = fmaf(ek_, w0_.x, pl_[0]); pl_[1] = fmaf(ek_, w0_.y, pl_[1]); \
            pl_[2] = fmaf(ek_, w0_.z, pl_[2]); pl_[3] = fmaf(ek_, w0_.w, pl_[3]); \
            pl_[4] = fmaf(ek_, w1_.x, pl_[4]); pl_[5] = fmaf(ek_, w1_.y, pl_[5]); \
            pl_[6] = fmaf(ek_, w1_.z, pl_[6]); pl_[7] = fmaf(ek_, w1_.w, pl_[7]); \
        }                                                                    \
        float gg_[8] = {GA.x, GA.y, GA.z, GA.w, GB.x, GB.y, GB.z, GB.w};     \
        float ss_ = 0.f;                                                     \
        _Pragma("unroll")                                                    \
        for (int j_ = 0; j_ < 8; ++j_) {                                     \
            float a_ = fmaf(pl_[j_], sinv, gg_[j_]);                         \
            e[j_] = __expf(a_);                                              \
            ss_ += e[j_];                                                    \
        }                                                                    \
        sinv = __builtin_amdgcn_rcpf(ss_);                                   \
        if (r < 32) {                                                        \
            f4v v0_ = (f4v){e[0] * sinv, e[1] * sinv, e[2] * sinv, e[3] * sinv}; \
            f4v v1_ = (f4v){e[4] * sinv, e[5] * sinv, e[6] * sinv, e[7] * sinv}; \
            st16(&yp[2 * (tt)], v0_);                                        \
            st16(&yp[2 * (tt) + 1], v1_);                                    \
        }                                                                    \
    } while (0)

    f4v* yp = (f4v*)(yseq + (size_t)b * T * 8);
    float e[8];
    float sinv;

    // ---- t = 0 from initl + gs[0] (plain loads, compiler-tracked) ----
    {
        const f4v* il4 = (const f4v*)(initl + b * 8);
        f4v i0 = il4[0], i1 = il4[1];
        const f4v* g4 = (const f4v*)(gs + b * 8);
        f4v G0 = g4[0], G1 = g4[1];
        float a[8];
        a[0] = fmaf(i0.x, TINV, G0.x); a[1] = fmaf(i0.y, TINV, G0.y);
        a[2] = fmaf(i0.z, TINV, G0.z); a[3] = fmaf(i0.w, TINV, G0.w);
        a[4] = fmaf(i1.x, TINV, G1.x); a[5] = fmaf(i1.y, TINV, G1.y);
        a[6] = fmaf(i1.z, TINV, G1.z); a[7] = fmaf(i1.w, TINV, G1.w);
        float ssum = 0.f;
#pragma unroll
        for (int j = 0; j < 8; ++j) { e[j] = __expf(a[j]); ssum += e[j]; }
        sinv = __builtin_amdgcn_rcpf(ssum);
        if (r < 32) {
            f4v y0v = (f4v){e[0] * sinv, e[1] * sinv, e[2] * sinv, e[3] * sinv};
            f4v y1v = (f4v){e[4] * sinv, e[5] * sinv, e[6] * sinv, e[7] * sinv};
            st16(&yp[0], y0v);
            st16(&yp[1], y1v);
        }
    }

    f4v LA[16], LB[16], gaA, gbA, gaB, gbB;

    __builtin_amdgcn_s_barrier();      // #0: slot 1 landed (producer vmcnt(36))
    SREAD(LA, gaA, gbA, 1);

    for (int t = 1; t < T - 1; t += 2) {
        __builtin_amdgcn_s_barrier();  // #t: slot t+1 landed
        LWAIT();                       // prior phase's SREAD retired
        SREAD(LB, gaB, gbB, t + 1);
        SCOMP(LA, gaA, gbA, t);

        __builtin_amdgcn_s_barrier();  // #t+1: slot t+2 landed
        LWAIT();
        SREAD(LA, gaA, gbA, t + 2);
        SCOMP(LB, gaB, gbB, t + 1);
    }
    __builtin_amdgcn_s_barrier();      // #511
    LWAIT();
    SCOMP(LA, gaA, gbA, T - 1);
#undef ISSUE
#undef SREAD
#undef LWAIT
#undef SCOMP
}

// ---------------- Kernel F: output einsums + lqlp merged --------------------
// blocks 0..1023: A/Q/B einsum tiles (64 bt each). blocks 1024..3071: lqlp
// (8 lanes per (b,t) row). Both depend only on completed yseq/logits and
// write disjoint d_out regions.
__global__ __launch_bounds__(256) void out_kernel(
    const float* __restrict__ yseq,
    const float* __restrict__ A, const float* __restrict__ Bm,
    const float* __restrict__ Q,
    const float* __restrict__ logits, const float* __restrict__ initl,
    float* __restrict__ logq, float* __restrict__ logp,
    float4* __restrict__ out4) {
    __shared__ float tab[5632];
    int tid = threadIdx.x;

    if (blockIdx.x >= 1024) {
        // ---------------- lqlp blocks ----------------
        int gtid = (blockIdx.x - 1024) * 256 + tid;   // (b*T + t)*8 + j
        int j = gtid & 7;
        int row = gtid >> 3;                           // b*T + t
        int b = row >> 9;
        int t = row & (T - 1);

        const float4* yt4 = (const float4*)(yseq + (size_t)row * 8);
        float4 ya = yt4[0], yb = yt4[1];
        float yt[8] = {ya.x, ya.y, ya.z, ya.w, yb.x, yb.y, yb.z, yb.w};

        float l[8];
        float lp;
        if (t == 0) {
            const float4* il4 = (const float4*)(initl + b * 8);
            float4 i0 = il4[0], i1 = il4[1];
            l[0] = i0.x; l[1] = i0.y; l[2] = i0.z; l[3] = i0.w;
            l[4] = i1.x; l[5] = i1.y; l[6] = i1.z; l[7] = i1.w;
            float sy = ((yt[0] + yt[1]) + (yt[2] + yt[3])) + ((yt[4] + yt[5]) + (yt[6] + yt[7]));
            lp = LOG_INV_K * sy;
        } else {
            const float4* yp4 = (const float4*)(yseq + (size_t)row * 8 - 8);
            float4 p0 = yp4[0], p1 = yp4[1];
            float ypv[8] = {p0.x, p0.y, p0.z, p0.w, p1.x, p1.y, p1.z, p1.w};
            float ypj = yseq[(size_t)row * 8 - 8 + j];
            const float4* L4 = (const float4*)(logits + ((size_t)t * B + b) * 64 + j * 8);
            float4 r0 = L4[0], r1 = L4[1];
            float c[8] = {ypj * r0.x, ypj * r0.y, ypj * r0.z, ypj * r0.w,
                          ypj * r1.x, ypj * r1.y, ypj * r1.z, ypj * r1.w};
#pragma unroll
            for (int s = 1; s <= 4; s <<= 1) {
#pragma unroll
                for (int m = 0; m < 8; ++m) c[m] += __shfl_xor(c[m], s, 64);
            }
#pragma unroll
            for (int m = 0; m < 8; ++m) l[m] = c[m] * 0.5f;
            float sy = ((ypv[0] + ypv[1]) + (ypv[2] + ypv[3])) + ((ypv[4] + ypv[5]) + (ypv[6] + ypv[7]));
            float acc = 0.f;
#pragma unroll
            for (int m = 0; m < 8; ++m) {
                float tp = fmaf(DPS, ypv[m], OFFV * sy);
                acc = fmaf(yt[m], logf(fmaxf(tp, 1e-8f)), acc);
            }
            lp = acc;
        }
        float m = fmaxf(fmaxf(fmaxf(l[0], l[1]), fmaxf(l[2], l[3])),
                        fmaxf(fmaxf(l[4], l[5]), fmaxf(l[6], l[7])));
        float se = 0.f;
#pragma unroll
        for (int m2 = 0; m2 < 8; ++m2) se += __expf(l[m2] - m);
        float lse = m + logf(se);
        float lq = 0.f;
#pragma unroll
        for (int m2 = 0; m2 < 8; ++m2) lq = fmaf(yt[m2], l[m2] - lse, lq);
        if (j == 0) {
            logq[row] = lq;
            logp[row] = lp;
        }
        return;
    }

    // ---------------- einsum blocks ----------------
    int bt0 = blockIdx.x * 64;
    {
        float4* t4 = (float4*)tab;
        const float4* A4 = (const float4*)A;
        const float4* B4 = (const float4*)Bm;
        const float4* Q4 = (const float4*)Q;
        for (int i2 = tid; i2 < 512; i2 += 256) t4[i2] = A4[i2];
        if (tid < 256) t4[512 + tid] = B4[tid];
        for (int i2 = tid; i2 < 512; i2 += 256) t4[768 + i2] = Q4[i2];
        const float4* Y4 = (const float4*)(yseq + (size_t)bt0 * 8);
        if (tid < 128) t4[1280 + tid] = Y4[tid];
    }
    __syncthreads();

    int wave = tid >> 6;
    int lane = tid & 63;
    const float4* t4 = (const float4*)tab;

    if (wave == 0 || wave == 1) {
        int tbase = (wave == 0) ? 0 : 768;
        size_t obase = (wave == 0) ? (size_t)(OUT_A / 4) : (size_t)(OUT_Q / 4);
        float4 wreg[8];
#pragma unroll
        for (int k = 0; k < 8; ++k) wreg[k] = t4[tbase + k * 64 + lane];
        for (int bt = 0; bt < 64; ++bt) {
            float4 ya = t4[1280 + bt * 2];
            float4 yb = t4[1280 + bt * 2 + 1];
            float yk[8] = {ya.x, ya.y, ya.z, ya.w, yb.x, yb.y, yb.z, yb.w};
            float4 v = make_float4(0.f, 0.f, 0.f, 0.f);
#pragma unroll
            for (int k = 0; k < 8; ++k) {
                v.x = fmaf(yk[k], wreg[k].x, v.x);
                v.y = fmaf(yk[k], wreg[k].y, v.y);
                v.z = fmaf(yk[k], wreg[k].z, v.z);
                v.w = fmaf(yk[k], wreg[k].w, v.w);
            }
            out4[obase + (size_t)(bt0 + bt) * 64 + lane] = v;
        }
    } else if (wave == 2 && lane < 32) {
        float4 wreg[8];
#pragma unroll
        for (int k = 0; k < 8; ++k) wreg[k] = t4[512 + k * 32 + lane];
        for (int bt = 0; bt < 64; ++bt) {
            float4 ya = t4[1280 + bt * 2];
            float4 yb = t4[1280 + bt * 2 + 1];
            float yk[8] = {ya.x, ya.y, ya.z, ya.w, yb.x, yb.y, yb.z, yb.w};
            float4 v = make_float4(0.f, 0.f, 0.f, 0.f);
#pragma unroll
            for (int k = 0; k < 8; ++k) {
                v.x = fmaf(yk[k], wreg[k].x, v.x);
                v.y = fmaf(yk[k], wreg[k].y, v.y);
                v.z = fmaf(yk[k], wreg[k].z, v.z);
                v.w = fmaf(yk[k], wreg[k].w, v.w);
            }
            out4[(size_t)(OUT_B / 4) + (size_t)(bt0 + bt) * 32 + lane] = v;
        }
    }
}

extern "C" void kernel_launch(void* const* d_in, const int* in_sizes, int n_in,
                              void* d_out, int out_size, void* d_ws, size_t ws_size,
                              hipStream_t stream) {
    const float* a_seq = (const float*)d_in[0];
    const float* A     = (const float*)d_in[1];
    const float* Bmat  = (const float*)d_in[2];
    const float* C     = (const float*)d_in[3];
    const float* Q     = (const float*)d_in[4];
    const float* wih_f = (const float*)d_in[5];
    const float* whh_f = (const float*)d_in[6];
    const float* bih_f = (const float*)d_in[7];
    const float* bhh_f = (const float*)d_in[8];
    const float* wih_b = (const float*)d_in[9];
    const float* whh_b = (const float*)d_in[10];
    const float* bih_b = (const float*)d_in[11];
    const float* bhh_b = (const float*)d_in[12];
    const float* wl    = (const float*)d_in[13];
    const float* bl    = (const float*)d_in[14];
    const float* wi    = (const float*)d_in[15];
    const float* bi    = (const float*)d_in[16];
    const float* u0    = (const float*)d_in[17];
    const float* useq  = (const float*)d_in[18];

    float* ws = (float*)d_ws;
    float* gx     = ws + WS_GX;
    float* hseq   = ws + WS_HSEQ;
    float* logits = ws + WS_LOGITS;   // aliases gx dir=0 half (written after GRU)
    float* initl  = ws + WS_INIT;
    float* yseq   = ws + WS_YSEQ;
    float* gs2    = ws + WS_YSEQ + (size_t)B * T * KK;  // after yseq (pre-GRU write)

    float* outf = (float*)d_out;
    float* logq = outf + OUT_LQ;
    float* logp = outf + OUT_LP;
    float4* outC = (float4*)(outf + OUT_C);

    gx_kernel<<<1024 + (T * B * KK + 191) / 192, 192, 0, stream>>>(
        a_seq, wih_f, bih_f, wih_b, bih_b, gx, u0, useq, gs2);
    gru_kernel<<<256, 64, 0, stream>>>(gx, whh_f, bhh_f, whh_b, bhh_b, hseq);
    logits_kernel<<<T * B / 4, 256, 0, stream>>>(hseq, wl, bl, wi, bi, logits, initl);
    scan_kernel<<<2048, 128, 0, stream>>>(logits, initl, gs2, yseq,
                                          (const float4*)C, outC);
    out_kernel<<<1024 + B * T * KK / 256, 256, 0, stream>>>(
        yseq, A, Bmat, Q, logits, initl, logq, logp, (float4*)d_out);
}

// Round 21
// 438.347 us; speedup vs baseline: 1.5032x; 1.0023x over previous
//
#include <hip/hip_runtime.h>
#include <math.h>

#define T 512
#define B 128
#define KK 8
#define HH 32
#define PP 32

// ws layout (floats)
#define WS_GX    0             /* gx [dir*B+b][t][96] = 12582912 floats */
#define WS_HSEQ  12582912
#define WS_LOGITS 0            /* alias gx dir=0 half: scaled logits [t][b][64], written after GRU */
#define WS_INIT  16777216
#define WS_YSEQ  16778240

// d_out layout (floats)
#define OUT_A    0
#define OUT_B    16777216
#define OUT_C    25165824
#define OUT_Q    58720256
#define OUT_LQ   75497472
#define OUT_LP   75563008

#define TINV 2.0f
#define PSTAY 0.9f
#define OFFV (0.1f / 7.0f)
#define DPS (PSTAY - OFFV)
#define LOG_INV_K (-2.0794415416798357f)

typedef float f4v __attribute__((ext_vector_type(4)));
typedef __attribute__((address_space(3))) float as3f;

// async DMA global->LDS, 16B/lane, opaque to compiler (no auto waitcnt insertion)
__device__ __forceinline__ void dma16(unsigned ldsbyte, int voffbyte, const void* sbase) {
    asm volatile("s_mov_b32 m0, %0\n\t"
                 "global_load_lds_dwordx4 %1, %2"
                 :: "s"(ldsbyte), "v"(voffbyte), "s"(sbase)
                 : "memory");
}
// stores kept in asm: compiler does not track them -> no per-iter vmcnt drains
__device__ __forceinline__ void st16(void* p, f4v v) {
    asm volatile("global_store_dwordx4 %0, %1, off" :: "v"(p), "v"(v) : "memory");
}
// pinned LDS read: output lives in registers, cannot be rematerialized at use
__device__ __forceinline__ f4v ldsr16(int addr) {
    f4v out;
    asm volatile("ds_read_b128 %0, %1" : "=v"(out) : "v"(addr));
    return out;
}
// pinned global loads: outputs live in registers; caller does counted vmcnt
__device__ __forceinline__ f4v ldg16(const void* p) {
    f4v out;
    asm volatile("global_load_dwordx4 %0, %1, off" : "=v"(out) : "v"(p) : "memory");
    return out;
}
__device__ __forceinline__ float ldg4(const void* p) {
    float out;
    asm volatile("global_load_dword %0, %1, off" : "=v"(out) : "v"(p) : "memory");
    return out;
}

// ---------------- Kernel A: gx tiled + gsc folded in as extra blocks --------
__global__ __launch_bounds__(192) void gx_kernel(
    const float* __restrict__ a_seq,
    const float* __restrict__ wih_f, const float* __restrict__ bih_f,
    const float* __restrict__ wih_b, const float* __restrict__ bih_b,
    float* __restrict__ gx,
    const float* __restrict__ u0, const float* __restrict__ useq,
    float* __restrict__ gs) {
    __shared__ float xt[64 * 32];
    if (blockIdx.x >= 1024) {
        int id = (blockIdx.x - 1024) * 192 + threadIdx.x;
        if (id < T * B * KK) {
            int j = id & 7;
            int b = (id >> 3) & 127;
            int t = id >> 10;
            float u = (t == 0) ? u0[b * 8 + j]
                               : useq[((size_t)b * (T - 1) + (t - 1)) * 8 + j];
            gs[id] = -logf(-logf(u)) * TINV;   // precise logf (u near 1 ill-conditioned)
        }
        return;
    }
    int blk = blockIdx.x;
    int b = blk >> 3;
    int t0 = (blk & 7) << 6;
    int g = threadIdx.x;            // 0..191
    int dir = (g >= 96) ? 1 : 0;
    int gg = dir ? (g - 96) : g;
    const float* w = dir ? wih_b : wih_f;
    const float* bv = dir ? bih_b : bih_f;

    {
        const float4* src = (const float4*)(a_seq + ((size_t)b * T + t0) * PP);
        float4* dst = (float4*)xt;
        for (int idx = g; idx < 512; idx += 192) dst[idx] = src[idx];
    }
    float wreg[32];
#pragma unroll
    for (int q = 0; q < 8; ++q) {
        float4 wv = *(const float4*)(w + (size_t)gg * PP + q * 4);
        wreg[q * 4 + 0] = wv.x; wreg[q * 4 + 1] = wv.y;
        wreg[q * 4 + 2] = wv.z; wreg[q * 4 + 3] = wv.w;
    }
    float bias = bv[gg];
    __syncthreads();

    float* op = gx + ((size_t)(dir * B + b) * T + t0) * 96 + gg;
#pragma unroll 4
    for (int r = 0; r < 64; ++r) {
        const float4* xr = (const float4*)(xt + r * 32);
        float acc = bias;
#pragma unroll
        for (int q = 0; q < 8; ++q) {
            float4 xv = xr[q];
            acc = fmaf(xv.x, wreg[q * 4 + 0], acc);
            acc = fmaf(xv.y, wreg[q * 4 + 1], acc);
            acc = fmaf(xv.z, wreg[q * 4 + 2], acc);
            acc = fmaf(xv.w, wreg[q * 4 + 3], acc);
        }
        op[(size_t)r * 96] = acc;
    }
}

// ---------------- Kernel B: GRU scan, split accumulator chains (r17) --------
__global__ __launch_bounds__(64, 1) void gru_kernel(
    const float* __restrict__ gx,
    const float* __restrict__ whh_f, const float* __restrict__ bhh_f,
    const float* __restrict__ whh_b, const float* __restrict__ bhh_b,
    float* __restrict__ hseq) {
    int cid = blockIdx.x;            // 0..255 = dir*128 + b
    int b = cid & 127;
    int dir = cid >> 7;
    int i = threadIdx.x & 31;
    const float* whh = dir ? whh_b : whh_f;
    const float* bhh = dir ? bhh_b : bhh_f;
    const float* gp0 = gx + (size_t)cid * (T * 96);

    f4v wr[8], wz[8], wn[8];
#pragma unroll
    for (int q = 0; q < 8; ++q) {
        wr[q] = ldg16(whh + (size_t)i * 32 + q * 4);
        wz[q] = ldg16(whh + (size_t)(32 + i) * 32 + q * 4);
        wn[q] = ldg16(whh + (size_t)(64 + i) * 32 + q * 4);
    }
    float bhr = ldg4(bhh + i);
    float bhz = ldg4(bhh + 32 + i);
    float bhn = ldg4(bhh + 64 + i);

    const float* p = gp0 + (dir ? (T - 1) * 96 : 0);
    int gstep = dir ? -96 : 96;
    int voff = (((dir ? (T - 1) : 0) * B + b) * 64 + dir * 32 + i) * 4;
    int vstep = dir ? -(B * 64 * 4) : (B * 64 * 4);

    float pxrA[8], pxzA[8], pxnA[8], pxrB[8], pxzB[8], pxnB[8];

#define LOADG(PR, PZ, PN, G0) do {                                             \
        _Pragma("unroll")                                                      \
        for (int u_ = 0; u_ < 8; ++u_) {                                       \
            int sc_ = (G0) * 8 + u_; if (sc_ > T - 1) sc_ = T - 1;             \
            const float* rp_ = p + sc_ * gstep;                                \
            PR[u_] = ldg4(rp_ + i);                                            \
            PZ[u_] = ldg4(rp_ + 32 + i);                                       \
            PN[u_] = ldg4(rp_ + 64 + i);                                       \
        }                                                                      \
    } while (0)

#define GWAIT(N) do {                                                          \
        asm volatile("s_waitcnt vmcnt(" #N ")" ::: "memory");                  \
        __builtin_amdgcn_sched_barrier(0);                                     \
    } while (0)

#define GSTEP(PR, PZ, PN, SLOT) do {                                           \
        float hj_[32];                                                         \
        _Pragma("unroll")                                                      \
        for (int jj = 0; jj < 32; ++jj)                                        \
            hj_[jj] = __uint_as_float(                                         \
                __builtin_amdgcn_readlane(__float_as_uint(h), jj));            \
        __builtin_amdgcn_sched_barrier(0);                                     \
        float r0_ = PR[SLOT] + bhr, r1_ = 0.f, r2_ = 0.f, r3_ = 0.f;           \
        float z0_ = PZ[SLOT] + bhz, z1_ = 0.f, z2_ = 0.f, z3_ = 0.f;           \
        float n0_ = bhn, n1_ = 0.f, n2_ = 0.f, n3_ = 0.f;                      \
        _Pragma("unroll")                                                      \
        for (int q_ = 0; q_ < 2; ++q_) {                                       \
            _Pragma("unroll")                                                  \
            for (int c_ = 0; c_ < 4; ++c_) {                                   \
                float hv_ = hj_[q_ * 4 + c_];                                  \
                r0_ = fmaf(wr[q_][c_], hv_, r0_);                              \
                z0_ = fmaf(wz[q_][c_], hv_, z0_);                              \
                n0_ = fmaf(wn[q_][c_], hv_, n0_);                              \
            }                                                                  \
        }                                                                      \
        _Pragma("unroll")                                                      \
        for (int q_ = 2; q_ < 4; ++q_) {                                       \
            _Pragma("unroll")                                                  \
            for (int c_ = 0; c_ < 4; ++c_) {                                   \
                float hv_ = hj_[q_ * 4 + c_];                                  \
                r1_ = fmaf(wr[q_][c_], hv_, r1_);                              \
                z1_ = fmaf(wz[q_][c_], hv_, z1_);                              \
                n1_ = fmaf(wn[q_][c_], hv_, n1_);                              \
            }                                                                  \
        }                                                                      \
        _Pragma("unroll")                                                      \
        for (int q_ = 4; q_ < 6; ++q_) {                                       \
            _Pragma("unroll")                                                  \
            for (int c_ = 0; c_ < 4; ++c_) {                                   \
                float hv_ = hj_[q_ * 4 + c_];                                  \
                r2_ = fmaf(wr[q_][c_], hv_, r2_);                              \
                z2_ = fmaf(wz[q_][c_], hv_, z2_);                              \
                n2_ = fmaf(wn[q_][c_], hv_, n2_);                              \
            }                                                                  \
        }                                                                      \
        _Pragma("unroll")                                                      \
        for (int q_ = 6; q_ < 8; ++q_) {                                       \
            _Pragma("unroll")                                                  \
            for (int c_ = 0; c_ < 4; ++c_) {                                   \
                float hv_ = hj_[q_ * 4 + c_];                                  \
                r3_ = fmaf(wr[q_][c_], hv_, r3_);                              \
                z3_ = fmaf(wz[q_][c_], hv_, z3_);                              \
                n3_ = fmaf(wn[q_][c_], hv_, n3_);                              \
            }                                                                  \
        }                                                                      \
        float hr_ = (r0_ + r1_) + (r2_ + r3_);                                 \
        float hz_ = (z0_ + z1_) + (z2_ + z3_);                                 \
        float hn_ = (n0_ + n1_) + (n2_ + n3_);                                 \
        float r_ = __builtin_amdgcn_rcpf(1.f + __expf(-hr_));                  \
        float z_ = __builtin_amdgcn_rcpf(1.f + __expf(-hz_));                  \
        float na_ = fmaf(r_, hn_, PN[SLOT]);                                   \
        float e2_ = __expf(-2.f * fabsf(na_));                                 \
        float n_ = copysignf((1.f - e2_) * __builtin_amdgcn_rcpf(1.f + e2_), na_); \
        h = fmaf(z_, h - n_, n_);                                              \
        asm volatile("global_store_dword %0, %1, %2"                           \
                     :: "v"(voff), "v"(h), "s"(hseq) : "memory");              \
        voff += vstep;                                                         \
    } while (0)

    LOADG(pxrA, pxzA, pxnA, 0);
    GWAIT(0);
    float h = 0.f;

    for (int gq = 0; gq < 32; ++gq) {
        LOADG(pxrB, pxzB, pxnB, 2 * gq + 1);
        GWAIT(32);
        GSTEP(pxrA, pxzA, pxnA, 0); GSTEP(pxrA, pxzA, pxnA, 1);
        GSTEP(pxrA, pxzA, pxnA, 2); GSTEP(pxrA, pxzA, pxnA, 3);
        GSTEP(pxrA, pxzA, pxnA, 4); GSTEP(pxrA, pxzA, pxnA, 5);
        GSTEP(pxrA, pxzA, pxnA, 6); GSTEP(pxrA, pxzA, pxnA, 7);
        LOADG(pxrA, pxzA, pxnA, 2 * gq + 2);
        GWAIT(32);
        GSTEP(pxrB, pxzB, pxnB, 0); GSTEP(pxrB, pxzB, pxnB, 1);
        GSTEP(pxrB, pxzB, pxnB, 2); GSTEP(pxrB, pxzB, pxnB, 3);
        GSTEP(pxrB, pxzB, pxnB, 4); GSTEP(pxrB, pxzB, pxnB, 5);
        GSTEP(pxrB, pxzB, pxnB, 6); GSTEP(pxrB, pxzB, pxnB, 7);
    }
#undef LOADG
#undef GWAIT
#undef GSTEP
}

// ---------------- Kernel C: logits (round-13 LDS-staged, unchanged) ---------
__global__ __launch_bounds__(256) void logits_kernel(
    const float* __restrict__ hseq,
    const float* __restrict__ wl, const float* __restrict__ bl,
    const float* __restrict__ wi, const float* __restrict__ bi,
    float* __restrict__ logits, float* __restrict__ initl) {
    __shared__ float wls[64 * 65];
    __shared__ float hrow[4][64];
    int tid = threadIdx.x;
    for (int i2 = tid; i2 < 1024; i2 += 256) {
        float4 v = ((const float4*)wl)[i2];
        int gr = i2 >> 4;
        int cc = (i2 & 15) * 4;
        float* d = &wls[gr * 65 + cc];
        d[0] = v.x; d[1] = v.y; d[2] = v.z; d[3] = v.w;
    }
    int q = tid >> 6;
    int tb = blockIdx.x * 4 + q;   // t*B + b
    int g = tid & 63;
    hrow[q][g] = hseq[(size_t)tb * 64 + g];
    __syncthreads();
    float acc = bl[g];
    const float* wrow = &wls[g * 65];
#pragma unroll
    for (int c = 0; c < 64; ++c) acc = fmaf(wrow[c], hrow[q][c], acc);
    logits[(size_t)tb * 64 + g] = acc * TINV;
    if (tb < B && g < 8) {
        float a2 = bi[g];
        const float* w2 = wi + (size_t)g * 64;
#pragma unroll
        for (int c = 0; c < 64; ++c) a2 = fmaf(w2[c], hrow[q][c], a2);
        initl[tb * 8 + g] = a2;
    }
}

// ---------------- Kernel D: scan (r13 core) + C-broadcast on idle CUs -------
__global__ __launch_bounds__(128, 1) void scan_kernel(
    const float* __restrict__ logits, const float* __restrict__ initl,
    const float* __restrict__ gs, float* __restrict__ yseq,
    const float4* __restrict__ Csrc, float4* __restrict__ outC) {
    __shared__ float lds[6][2304];   // 6 slots x (32*64 logits + 32*8 gs)
    int tid = threadIdx.x;
    if (blockIdx.x >= 4) {
        // ---------------- C-broadcast blocks ----------------
        size_t stride = (size_t)(2048 - 4) * 128;
        for (size_t idx = (size_t)(blockIdx.x - 4) * 128 + tid;
             idx < (size_t)B * T * 128; idx += stride) {
            outC[idx] = Csrc[idx & 127];
        }
        return;
    }
    int wave = tid >> 6;
    int r = tid & 63;
    int b0 = blockIdx.x * 32;
    int b = b0 + (r & 31);
    int k15 = r & 15;

    unsigned ldsU = (unsigned)(unsigned long long)(as3f*)(&lds[0][0]);

#define ISSUE(tt, sl) do {                                                   \
        unsigned lb_ = ldsU + (unsigned)((sl) * 9216);                       \
        const char* bt_ = (const char*)logits + (size_t)(tt) * 32768;        \
        const char* gt_ = (const char*)gs + (size_t)(tt) * 4096;             \
        dma16(lb_ + 0 * 1024u, lof[0], bt_);                                 \
        dma16(lb_ + 1 * 1024u, lof[1], bt_);                                 \
        dma16(lb_ + 2 * 1024u, lof[2], bt_);                                 \
        dma16(lb_ + 3 * 1024u, lof[3], bt_);                                 \
        dma16(lb_ + 4 * 1024u, lof[4], bt_);                                 \
        dma16(lb_ + 5 * 1024u, lof[5], bt_);                                 \
        dma16(lb_ + 6 * 1024u, lof[6], bt_);                                 \
        dma16(lb_ + 7 * 1024u, lof[7], bt_);                                 \
        dma16(lb_ + 8192u, gof, gt_);                                        \
    } while (0)

    if (wave == 1) {
        // ---------------- DMA producer wave ----------------
        int lof[8];
#pragma unroll
        for (int q = 0; q < 8; ++q) {
            int rr = q * 4 + (r >> 4);         // tile row 0..31
            int cc = r & 15;                   // linear f4v col in LDS
            lof[q] = (((b0 + rr) * 64) + ((cc ^ (rr & 15)) << 2)) << 2;
        }
        int gof;
        {
            int rg = r >> 1;
            int cc = r & 1;
            gof = (((b0 + rg) * 8) + ((cc ^ (rg & 1)) << 2)) << 2;
        }
#pragma unroll
        for (int p = 1; p <= 5; ++p) ISSUE(p, p);
        asm volatile("s_waitcnt vmcnt(36)" ::: "memory");   // slot 1 landed
        __builtin_amdgcn_s_barrier();                        // #0
        for (int t = 1; t < T; ++t) {
            asm volatile("s_waitcnt vmcnt(27)" ::: "memory"); // slot t+1 landed
            __builtin_amdgcn_s_barrier();                     // #t
            int tp = t + 5; if (tp > T - 1) tp = T - 1;
            ISSUE(tp, (t + 5) % 6);
        }
        return;
    }

    // ---------------- compute consumer wave ----------------
    unsigned rbase = ldsU + (unsigned)((r & 31) * 256);
    unsigned gbase = ldsU + 8192u + (unsigned)((r & 31) * 32);

#define SREAD(LL, GA, GB, tt) do {                                           \
        int so_ = ((tt) % 6) * 9216;                                         \
        _Pragma("unroll")                                                    \
        for (int m_ = 0; m_ < 16; ++m_)                                      \
            LL[m_] = ldsr16((int)(rbase + so_ + ((m_ ^ k15) << 4)));         \
        GA = ldsr16((int)(gbase + so_ + ((r & 1) << 4)));                    \
        GB = ldsr16((int)(gbase + so_ + (((r & 1) ^ 1) << 4)));              \
    } while (0)

#define LWAIT() do {                                                         \
        asm volatile("s_waitcnt lgkmcnt(0)" ::: "memory");                   \
        __builtin_amdgcn_sched_barrier(0);                                   \
    } while (0)

#define SCOMP(LL, GA, GB, tt) do {                                           \
        float pl_[8];                                                        \
        _Pragma("unroll")                                                    \
        for (int j_ = 0; j_ < 8; ++j_) pl_[j_] = 0.f;                        \
        _Pragma("unroll")                                                    \
        for (int k_ = 0; k_ < 8; ++k_) {                                     \
            f4v w0_ = LL[2 * k_], w1_ = LL[2 * k_ + 1];                      \
            float ek_ = e[k_];                                               \
            pl_[0] = fmaf(ek_, w0_.x, pl_[0]); pl_[1] = fmaf(ek_, w0_.y, pl_[1]); \
            pl_[2] = fmaf(ek_, w0_.z, pl_[2]); pl_[3] = fmaf(ek_, w0_.w, pl_[3]); \
            pl_[4] = fmaf(ek_, w1_.x, pl_[4]); pl_[5] = fmaf(ek_, w1_.y, pl_[5]); \
            pl_[6] = fmaf(ek_, w1_.z, pl_[6]); pl_[7] = fmaf(ek_, w1_.w, pl_[7]); \
        }                                                                    \
        float gg_[8] = {GA.x, GA.y, GA.z, GA.w, GB.x, GB.y, GB.z, GB.w};     \
        float ss_ = 0.f;                                                     \
        _Pragma("unroll")                                                    \
        for (int j_ = 0; j_ < 8; ++j_) {                                     \
            float a_ = fmaf(pl_[j_], sinv, gg_[j_]);                         \
            e[j_] = __expf(a_);                                              \
            ss_ += e[j_];                                                    \
        }                                                                    \
        sinv = __builtin_amdgcn_rcpf(ss_);                                   \
        if (r < 32) {                                                        \
            f4v v0_ = (f4v){e[0] * sinv, e[1] * sinv, e[2] * sinv, e[3] * sinv}; \
            f4v v1_ = (f4v){e[4] * sinv, e[5] * sinv, e[6] * sinv, e[7] * sinv}; \
            st16(&yp[2 * (tt)], v0_);                                        \
            st16(&yp[2 * (tt) + 1], v1_);                                    \
        }                                                                    \
    } while (0)

    f4v* yp = (f4v*)(yseq + (size_t)b * T * 8);
    float e[8];
    float sinv;

    // ---- t = 0 from initl + gs[0] (plain loads, compiler-tracked) ----
    {
        const f4v* il4 = (const f4v*)(initl + b * 8);
        f4v i0 = il4[0], i1 = il4[1];
        const f4v* g4 = (const f4v*)(gs + b * 8);
        f4v G0 = g4[0], G1 = g4[1];
        float a[8];
        a[0] = fmaf(i0.x, TINV, G0.x); a[1] = fmaf(i0.y, TINV, G0.y);
        a[2] = fmaf(i0.z, TINV, G0.z); a[3] = fmaf(i0.w, TINV, G0.w);
        a[4] = fmaf(i1.x, TINV, G1.x); a[5] = fmaf(i1.y, TINV, G1.y);
        a[6] = fmaf(i1.z, TINV, G1.z); a[7] = fmaf(i1.w, TINV, G1.w);
        float ssum = 0.f;
#pragma unroll
        for (int j = 0; j < 8; ++j) { e[j] = __expf(a[j]); ssum += e[j]; }
        sinv = __builtin_amdgcn_rcpf(ssum);
        if (r < 32) {
            f4v y0v = (f4v){e[0] * sinv, e[1] * sinv, e[2] * sinv, e[3] * sinv};
            f4v y1v = (f4v){e[4] * sinv, e[5] * sinv, e[6] * sinv, e[7] * sinv};
            st16(&yp[0], y0v);
            st16(&yp[1], y1v);
        }
    }

    f4v LA[16], LB[16], gaA, gbA, gaB, gbB;

    __builtin_amdgcn_s_barrier();      // #0: slot 1 landed (producer vmcnt(36))
    SREAD(LA, gaA, gbA, 1);

    for (int t = 1; t < T - 1; t += 2) {
        __builtin_amdgcn_s_barrier();  // #t: slot t+1 landed
        LWAIT();                       // prior phase's SREAD retired
        SREAD(LB, gaB, gbB, t + 1);
        SCOMP(LA, gaA, gbA, t);

        __builtin_amdgcn_s_barrier();  // #t+1: slot t+2 landed
        LWAIT();
        SREAD(LA, gaA, gbA, t + 2);
        SCOMP(LB, gaB, gbB, t + 1);
    }
    __builtin_amdgcn_s_barrier();      // #511
    LWAIT();
    SCOMP(LA, gaA, gbA, T - 1);
#undef ISSUE
#undef SREAD
#undef LWAIT
#undef SCOMP
}

// ---------------- Kernel F: output einsums + lqlp merged --------------------
__global__ __launch_bounds__(256) void out_kernel(
    const float* __restrict__ yseq,
    const float* __restrict__ A, const float* __restrict__ Bm,
    const float* __restrict__ Q,
    const float* __restrict__ logits, const float* __restrict__ initl,
    float* __restrict__ logq, float* __restrict__ logp,
    float4* __restrict__ out4) {
    __shared__ float tab[5632];
    int tid = threadIdx.x;

    if (blockIdx.x >= 1024) {
        // ---------------- lqlp blocks ----------------
        int gtid = (blockIdx.x - 1024) * 256 + tid;   // (b*T + t)*8 + j
        int j = gtid & 7;
        int row = gtid >> 3;                           // b*T + t
        int b = row >> 9;
        int t = row & (T - 1);

        const float4* yt4 = (const float4*)(yseq + (size_t)row * 8);
        float4 ya = yt4[0], yb = yt4[1];
        float yt[8] = {ya.x, ya.y, ya.z, ya.w, yb.x, yb.y, yb.z, yb.w};

        float l[8];
        float lp;
        if (t == 0) {
            const float4* il4 = (const float4*)(initl + b * 8);
            float4 i0 = il4[0], i1 = il4[1];
            l[0] = i0.x; l[1] = i0.y; l[2] = i0.z; l[3] = i0.w;
            l[4] = i1.x; l[5] = i1.y; l[6] = i1.z; l[7] = i1.w;
            float sy = ((yt[0] + yt[1]) + (yt[2] + yt[3])) + ((yt[4] + yt[5]) + (yt[6] + yt[7]));
            lp = LOG_INV_K * sy;
        } else {
            const float4* yp4 = (const float4*)(yseq + (size_t)row * 8 - 8);
            float4 p0 = yp4[0], p1 = yp4[1];
            float ypv[8] = {p0.x, p0.y, p0.z, p0.w, p1.x, p1.y, p1.z, p1.w};
            float ypj = yseq[(size_t)row * 8 - 8 + j];
            const float4* L4 = (const float4*)(logits + ((size_t)t * B + b) * 64 + j * 8);
            float4 r0 = L4[0], r1 = L4[1];
            float c[8] = {ypj * r0.x, ypj * r0.y, ypj * r0.z, ypj * r0.w,
                          ypj * r1.x, ypj * r1.y, ypj * r1.z, ypj * r1.w};
#pragma unroll
            for (int s = 1; s <= 4; s <<= 1) {
#pragma unroll
                for (int m = 0; m < 8; ++m) c[m] += __shfl_xor(c[m], s, 64);
            }
#pragma unroll
            for (int m = 0; m < 8; ++m) l[m] = c[m] * 0.5f;
            float sy = ((ypv[0] + ypv[1]) + (ypv[2] + ypv[3])) + ((ypv[4] + ypv[5]) + (ypv[6] + ypv[7]));
            float acc = 0.f;
#pragma unroll
            for (int m = 0; m < 8; ++m) {
                float tp = fmaf(DPS, ypv[m], OFFV * sy);
                acc = fmaf(yt[m], logf(fmaxf(tp, 1e-8f)), acc);
            }
            lp = acc;
        }
        float m = fmaxf(fmaxf(fmaxf(l[0], l[1]), fmaxf(l[2], l[3])),
                        fmaxf(fmaxf(l[4], l[5]), fmaxf(l[6], l[7])));
        float se = 0.f;
#pragma unroll
        for (int m2 = 0; m2 < 8; ++m2) se += __expf(l[m2] - m);
        float lse = m + logf(se);
        float lq = 0.f;
#pragma unroll
        for (int m2 = 0; m2 < 8; ++m2) lq = fmaf(yt[m2], l[m2] - lse, lq);
        if (j == 0) {
            logq[row] = lq;
            logp[row] = lp;
        }
        return;
    }

    // ---------------- einsum blocks ----------------
    int bt0 = blockIdx.x * 64;
    {
        float4* t4 = (float4*)tab;
        const float4* A4 = (const float4*)A;
        const float4* B4 = (const float4*)Bm;
        const float4* Q4 = (const float4*)Q;
        for (int i2 = tid; i2 < 512; i2 += 256) t4[i2] = A4[i2];
        if (tid < 256) t4[512 + tid] = B4[tid];
        for (int i2 = tid; i2 < 512; i2 += 256) t4[768 + i2] = Q4[i2];
        const float4* Y4 = (const float4*)(yseq + (size_t)bt0 * 8);
        if (tid < 128) t4[1280 + tid] = Y4[tid];
    }
    __syncthreads();

    int wave = tid >> 6;
    int lane = tid & 63;
    const float4* t4 = (const float4*)tab;

    if (wave == 0 || wave == 1) {
        int tbase = (wave == 0) ? 0 : 768;
        size_t obase = (wave == 0) ? (size_t)(OUT_A / 4) : (size_t)(OUT_Q / 4);
        float4 wreg[8];
#pragma unroll
        for (int k = 0; k < 8; ++k) wreg[k] = t4[tbase + k * 64 + lane];
        for (int bt = 0; bt < 64; ++bt) {
            float4 ya = t4[1280 + bt * 2];
            float4 yb = t4[1280 + bt * 2 + 1];
            float yk[8] = {ya.x, ya.y, ya.z, ya.w, yb.x, yb.y, yb.z, yb.w};
            float4 v = make_float4(0.f, 0.f, 0.f, 0.f);
#pragma unroll
            for (int k = 0; k < 8; ++k) {
                v.x = fmaf(yk[k], wreg[k].x, v.x);
                v.y = fmaf(yk[k], wreg[k].y, v.y);
                v.z = fmaf(yk[k], wreg[k].z, v.z);
                v.w = fmaf(yk[k], wreg[k].w, v.w);
            }
            out4[obase + (size_t)(bt0 + bt) * 64 + lane] = v;
        }
    } else if (wave == 2 && lane < 32) {
        float4 wreg[8];
#pragma unroll
        for (int k = 0; k < 8; ++k) wreg[k] = t4[512 + k * 32 + lane];
        for (int bt = 0; bt < 64; ++bt) {
            float4 ya = t4[1280 + bt * 2];
            float4 yb = t4[1280 + bt * 2 + 1];
            float yk[8] = {ya.x, ya.y, ya.z, ya.w, yb.x, yb.y, yb.z, yb.w};
            float4 v = make_float4(0.f, 0.f, 0.f, 0.f);
#pragma unroll
            for (int k = 0; k < 8; ++k) {
                v.x = fmaf(yk[k], wreg[k].x, v.x);
                v.y = fmaf(yk[k], wreg[k].y, v.y);
                v.z = fmaf(yk[k], wreg[k].z, v.z);
                v.w = fmaf(yk[k], wreg[k].w, v.w);
            }
            out4[(size_t)(OUT_B / 4) + (size_t)(bt0 + bt) * 32 + lane] = v;
        }
    }
}

extern "C" void kernel_launch(void* const* d_in, const int* in_sizes, int n_in,
                              void* d_out, int out_size, void* d_ws, size_t ws_size,
                              hipStream_t stream) {
    const float* a_seq = (const float*)d_in[0];
    const float* A     = (const float*)d_in[1];
    const float* Bmat  = (const float*)d_in[2];
    const float* C     = (const float*)d_in[3];
    const float* Q     = (const float*)d_in[4];
    const float* wih_f = (const float*)d_in[5];
    const float* whh_f = (const float*)d_in[6];
    const float* bih_f = (const float*)d_in[7];
    const float* bhh_f = (const float*)d_in[8];
    const float* wih_b = (const float*)d_in[9];
    const float* whh_b = (const float*)d_in[10];
    const float* bih_b = (const float*)d_in[11];
    const float* bhh_b = (const float*)d_in[12];
    const float* wl    = (const float*)d_in[13];
    const float* bl    = (const float*)d_in[14];
    const float* wi    = (const float*)d_in[15];
    const float* bi    = (const float*)d_in[16];
    const float* u0    = (const float*)d_in[17];
    const float* useq  = (const float*)d_in[18];

    float* ws = (float*)d_ws;
    float* gx     = ws + WS_GX;
    float* hseq   = ws + WS_HSEQ;
    float* logits = ws + WS_LOGITS;   // aliases gx dir=0 half (written after GRU)
    float* initl  = ws + WS_INIT;
    float* yseq   = ws + WS_YSEQ;
    float* gs2    = ws + WS_YSEQ + (size_t)B * T * KK;  // after yseq (pre-GRU write)

    float* outf = (float*)d_out;
    float* logq = outf + OUT_LQ;
    float* logp = outf + OUT_LP;
    float4* outC = (float4*)(outf + OUT_C);

    gx_kernel<<<1024 + (T * B * KK + 191) / 192, 192, 0, stream>>>(
        a_seq, wih_f, bih_f, wih_b, bih_b, gx, u0, useq, gs2);
    gru_kernel<<<256, 64, 0, stream>>>(gx, whh_f, bhh_f, whh_b, bhh_b, hseq);
    logits_kernel<<<T * B / 4, 256, 0, stream>>>(hseq, wl, bl, wi, bi, logits, initl);
    scan_kernel<<<2048, 128, 0, stream>>>(logits, initl, gs2, yseq,
                                          (const float4*)C, outC);
    out_kernel<<<1024 + B * T * KK / 256, 256, 0, stream>>>(
        yseq, A, Bmat, Q, logits, initl, logq, logp, (float4*)d_out);
}